// Round 7
// baseline (176.147 us; speedup 1.0000x reference)
//
#include <hip/hip_runtime.h>
#include <hip/hip_bf16.h>

typedef float f4vec  __attribute__((ext_vector_type(4)));
typedef float f16vec __attribute__((ext_vector_type(16)));
typedef float f64vec __attribute__((ext_vector_type(64)));
typedef short s8vec  __attribute__((ext_vector_type(8)));

#define B_DIM 64
#define N_DIM 64
#define D_DIM 9216
#define SPLIT 8
#define CHUNK 1152          // D_DIM / SPLIT
#define NSTEP (CHUNK / 64)  // 18

// ws layout (bytes):
//   Spart    @ 0        : 64*8*4096*4 = 8388608
//   meanPart @ 8388608  : 64*8*64*4   = 131072
//   Cout     @ 8519680  : 64*64*4     = 16384   (c = inv_L @ mean, fp32)
//   Mb(bf16) @ 8536064  : 64*4096*2   = 524288  (M = inv_L - I, row-major)

__device__ __forceinline__ short f2bf(float f) {
  union { __hip_bfloat16 h; short s; } u;
  u.h = __float2bfloat16(f);
  return u.s;
}

// v_readlane: static VGPR index, runtime-uniform (SGPR) lane index is legal.
__device__ __forceinline__ float rdlane(float v, int l) {
  union { float f; int i; } u;
  u.f = v;
  u.i = __builtin_amdgcn_readlane(u.i, l);
  return u.f;
}

// ---------------- Kernel 1: partial Gram + row-sum partials ----------------
__global__ __launch_bounds__(256) void k_cov_partial(
    const float* __restrict__ x, float* __restrict__ Spart,
    float* __restrict__ meanPart) {
  const int s = blockIdx.x, b = blockIdx.y;
  const int t = threadIdx.x;
  const int lane = t & 63, w = t >> 6;
  const int wr = w >> 1, wc = w & 1;
  const int hi = lane >> 5;

  __shared__ float T[64 * 64];

  const float* xb = x + (size_t)b * N_DIM * D_DIM + (size_t)s * CHUNK;
  const int jrow = t >> 2, q = t & 3;
  const float* xrow = xb + (size_t)jrow * D_DIM;

  f16vec acc;
#pragma unroll
  for (int r = 0; r < 16; ++r) acc[r] = 0.0f;
  float msum = 0.0f;

  const int r_a = 32 * wr + (lane & 31);
  const int r_b = 32 * wc + (lane & 31);

  f4vec v[4];
#pragma unroll
  for (int i = 0; i < 4; ++i)
    v[i] = *reinterpret_cast<const f4vec*>(xrow + (i * 4 + q) * 4);

  for (int step = 0; step < NSTEP; ++step) {
    __syncthreads();  // previous step's frag reads done; LDS free
#pragma unroll
    for (int i = 0; i < 4; ++i) {
      const int f = i * 4 + q;
      msum += v[i].x + v[i].y + v[i].z + v[i].w;
      *reinterpret_cast<f4vec*>(&T[jrow * 64 + ((f ^ (jrow & 15)) << 2)]) = v[i];
    }
    __syncthreads();  // tile ready
    if (step + 1 < NSTEP) {
      const float* xn = xrow + (step + 1) * 64;
#pragma unroll
      for (int i = 0; i < 4; ++i)
        v[i] = *reinterpret_cast<const f4vec*>(xn + (i * 4 + q) * 4);
    }
#pragma unroll
    for (int ks = 0; ks < 4; ++ks) {
      const int c0 = ks * 4 + hi * 2;
      f4vec a0 = *reinterpret_cast<const f4vec*>(
          &T[r_a * 64 + ((c0 ^ (r_a & 15)) << 2)]);
      f4vec a1 = *reinterpret_cast<const f4vec*>(
          &T[r_a * 64 + (((c0 + 1) ^ (r_a & 15)) << 2)]);
      f4vec b0 = *reinterpret_cast<const f4vec*>(
          &T[r_b * 64 + ((c0 ^ (r_b & 15)) << 2)]);
      f4vec b1 = *reinterpret_cast<const f4vec*>(
          &T[r_b * 64 + (((c0 + 1) ^ (r_b & 15)) << 2)]);
      s8vec af, bf;
      af[0]=f2bf(a0.x); af[1]=f2bf(a0.y); af[2]=f2bf(a0.z); af[3]=f2bf(a0.w);
      af[4]=f2bf(a1.x); af[5]=f2bf(a1.y); af[6]=f2bf(a1.z); af[7]=f2bf(a1.w);
      bf[0]=f2bf(b0.x); bf[1]=f2bf(b0.y); bf[2]=f2bf(b0.z); bf[3]=f2bf(b0.w);
      bf[4]=f2bf(b1.x); bf[5]=f2bf(b1.y); bf[6]=f2bf(b1.z); bf[7]=f2bf(b1.w);
      acc = __builtin_amdgcn_mfma_f32_32x32x16_bf16(af, bf, acc, 0, 0, 0);
    }
  }

  msum += __shfl_xor(msum, 1);
  msum += __shfl_xor(msum, 2);
  if (q == 0) meanPart[(b * SPLIT + s) * 64 + jrow] = msum;

  float* Sp = Spart + (size_t)(b * SPLIT + s) * 4096;
#pragma unroll
  for (int r = 0; r < 16; ++r) {
    const int i = 32 * wr + (r & 3) + 8 * (r >> 2) + 4 * hi;
    const int j = 32 * wc + (lane & 31);
    Sp[i * 64 + j] = acc[r];
  }
}

// ------- Kernel 2: in-register Cholesky + triangular inverse (per wave) ----
// One wave per block (one batch); lane i holds row i.
// Round-7 change: a[]/y[] were float[64] arrays -> rounds 5/6 allocated only
// 104 VGPRs (< the 135+ live floats) and pushed state to scratch; every
// access in the runtime-k/i loops was a scratch round-trip (~278K cyc/wave,
// VALUBusy 1.5%). Now ext_vector_type(64) with compile-time-constant
// element indices: insert/extract are pure register ops (like the f16vec
// MFMA accumulators), so the state is register-file-resident by
// construction. Code stays looped (I$-resident, ~2KB bodies).
__global__ __launch_bounds__(64, 1) void k_chol_inv(
    const float* __restrict__ Spart, const float* __restrict__ meanPart,
    unsigned short* __restrict__ Mb, float* __restrict__ Cout) {
  const int lane = threadIdx.x;   // 0..63; lane i holds row i
  const int b = blockIdx.x;

  f64vec a;

  // Reduce 8 Gram partials for row `lane` (L2/L3-resident).
  {
    const float* base = Spart + (size_t)(b * SPLIT) * 4096 + lane * 64;
#pragma unroll
    for (int j4 = 0; j4 < 16; ++j4) {
      f4vec s = *reinterpret_cast<const f4vec*>(base + j4 * 4);
#pragma unroll
      for (int p = 1; p < SPLIT; ++p)
        s += *reinterpret_cast<const f4vec*>(base + (size_t)p * 4096 + j4 * 4);
      a[j4 * 4 + 0] = s.x; a[j4 * 4 + 1] = s.y;
      a[j4 * 4 + 2] = s.z; a[j4 * 4 + 3] = s.w;
    }
  }

  float mown = 0.0f;
#pragma unroll
  for (int p = 0; p < SPLIT; ++p)
    mown += meanPart[(b * SPLIT + p) * 64 + lane];
  mown *= (1.0f / D_DIM);

  // cov[i][j] = (S[i][j] - D*m_i*m_j) / (D-1)
  {
    const float invD1 = 1.0f / (float)(D_DIM - 1);
    const float miD = mown * (float)D_DIM;
#pragma unroll
    for (int j = 0; j < 64; ++j)
      a[j] = (a[j] - miD * rdlane(mown, j)) * invD1;
  }

  // In-register right-looking Cholesky, unscaled pivots. m = pivot column k
  // (lane i's m = A[i][k]), maintained by an 8-wide cndmask capture chain.
  // Broadcast row k via trailing-block symmetry: A[k][j] = rdlane(m, j).
  float m = a[0];
#pragma clang loop unroll(disable)
  for (int k = 0; k < 64; ++k) {
    const float d = rdlane(m, k);                   // pivot d_k
    const float inv = __builtin_amdgcn_rcpf(d);
    const float f = (lane > k) ? m * inv : 0.0f;
#pragma unroll
    for (int jb = 0; jb < 8; ++jb) {
      if (jb * 8 + 8 > k) {                // block has some j > k (uniform)
        const bool mixed = (jb * 8 <= k);
#pragma unroll
        for (int jj = 0; jj < 8; ++jj) {
          const int j = jb * 8 + jj;
          const float bc = rdlane(m, j);   // A[k][j] by trailing symmetry
          float upd = f * bc;
          if (mixed) upd = (j > k) ? upd : 0.0f;  // keep frozen part intact
          a[j] -= upd;
        }
      }
    }
    // Capture next pivot column m = a[k+1] (post-update). k=63: no-op.
#pragma unroll
    for (int jb = 0; jb < 8; ++jb) {
      if (((k + 1) >> 3) == jb) {
#pragma unroll
        for (int jj = 0; jj < 8; ++jj) {
          const int j = jb * 8 + jj;
          m = (j == k + 1) ? a[j] : m;
        }
      }
    }
  }

  // Capture own diagonal d_lane; init y. (Upper-triangle a-values are only
  // ever multiplied by y[j]=0 in fwd-sub, so no zeroing pass is needed.)
  float diag = 0.0f;
  f64vec y;
#pragma unroll
  for (int j = 0; j < 64; ++j) {
    diag = (j == lane) ? a[j] : diag;
    y[j] = 0.0f;
  }
  const float sqd_own = __builtin_amdgcn_sqrtf(diag);

  // Forward substitution on A-bar; lane c owns column c of Y = inv(A-bar).
  // inv_L = diag(sqrt(d)) * Y. a[] is frozen -> readlanes are hazard-free.
  const size_t mb_base = (size_t)b * 4096;
#pragma clang loop unroll(disable)
  for (int i = 0; i < 64; ++i) {
    const float d = rdlane(diag, i);
    float s0 = 0.0f, s1 = 0.0f, s2 = 0.0f, s3 = 0.0f;
#pragma unroll
    for (int jb = 0; jb < 8; ++jb) {
      if (jb * 8 <= i) {                   // blocks fully above i: y==0
#pragma unroll
        for (int jj = 0; jj < 8; ++jj) {
          const int j = jb * 8 + jj;
          const float bc = rdlane(a[j], i);  // A-bar[i][j], uniform
          const float pr = bc * y[j];
          if ((jj & 3) == 0) s0 += pr;
          else if ((jj & 3) == 1) s1 += pr;
          else if ((jj & 3) == 2) s2 += pr;
          else s3 += pr;
        }
      }
    }
    const float invd = __builtin_amdgcn_rcpf(d);
    const float del = (lane == i) ? 1.0f : 0.0f;
    const float yi = (del - ((s0 + s1) + (s2 + s3))) * invd;
    // y[i] = yi via 8-wide capture chain in the block containing i.
#pragma unroll
    for (int jb = 0; jb < 8; ++jb) {
      if ((i >> 3) == jb) {
#pragma unroll
        for (int jj = 0; jj < 8; ++jj) {
          const int j = jb * 8 + jj;
          y[j] = (j == i) ? yi : y[j];
        }
      }
    }
    const float xv = yi * __builtin_amdgcn_sqrtf(d);  // inv_L[i][lane]
    // M = inv_L - I, row i: coalesced u16 store.
    Mb[mb_base + i * 64 + lane] = (unsigned short)f2bf(xv - del);
  }

  // Cvec[i] = sqrt(d_i) * sum_c Y[i][c]*mean_c. 64 INDEPENDENT butterflies;
  // lane i ends holding S_i, scales by its own sqrt(diag), coalesced store.
  float res = 0.0f;
#pragma unroll
  for (int i = 0; i < 64; ++i) {
    float t2 = y[i] * mown;
    t2 += __shfl_xor(t2, 1);
    t2 += __shfl_xor(t2, 2);
    t2 += __shfl_xor(t2, 4);
    t2 += __shfl_xor(t2, 8);
    t2 += __shfl_xor(t2, 16);
    t2 += __shfl_xor(t2, 32);
    res = (lane == i) ? t2 : res;
  }
  Cout[b * 64 + lane] = res * sqd_own;
}

// ---------------- Kernel 3: out = x + M@x - c*1^T  (LDS-free) --------------
__global__ __launch_bounds__(256) void k_whiten(
    const float* __restrict__ x, const float* __restrict__ Cvec,
    const unsigned short* __restrict__ Mb, float* __restrict__ out) {
  const int b = blockIdx.y;
  const int t = threadIdx.x;
  const int wid = t >> 6, lane = t & 63;
  const int lo = lane & 31, hi = lane >> 5;

  s8vec mfrag[2][4];
  const unsigned short* Mbb = Mb + (size_t)b * 4096;
#pragma unroll
  for (int wr = 0; wr < 2; ++wr)
#pragma unroll
    for (int ks = 0; ks < 4; ++ks)
      mfrag[wr][ks] = *reinterpret_cast<const s8vec*>(
          Mbb + (32 * wr + lo) * 64 + ks * 16 + hi * 8);

  float cv[2][16];
  const float* cb = Cvec + b * 64;
#pragma unroll
  for (int wr = 0; wr < 2; ++wr)
#pragma unroll
    for (int r = 0; r < 16; ++r)
      cv[wr][r] = cb[32 * wr + (r & 3) + 8 * (r >> 2) + 4 * hi];

  const float* xb = x + (size_t)b * N_DIM * D_DIM;
  float* ob = out + (size_t)b * N_DIM * D_DIM;

#pragma unroll
  for (int n = 0; n < 2; ++n) {
    const int d0 = blockIdx.x * 256 + wid * 64 + n * 32;
    f16vec acc0, acc1;
#pragma unroll
    for (int r = 0; r < 16; ++r) { acc0[r] = 0.0f; acc1[r] = 0.0f; }

#pragma unroll
    for (int ks = 0; ks < 4; ++ks) {
      const float* colp = xb + (size_t)(16 * ks + 8 * hi) * D_DIM + d0 + lo;
      s8vec bf;
#pragma unroll
      for (int e = 0; e < 8; ++e) bf[e] = f2bf(colp[(size_t)e * D_DIM]);
      acc0 = __builtin_amdgcn_mfma_f32_32x32x16_bf16(mfrag[0][ks], bf, acc0, 0, 0, 0);
      acc1 = __builtin_amdgcn_mfma_f32_32x32x16_bf16(mfrag[1][ks], bf, acc1, 0, 0, 0);
    }

#pragma unroll
    for (int r = 0; r < 16; ++r) {
      const int row = (r & 3) + 8 * (r >> 2) + 4 * hi;
      const size_t off0 = (size_t)row * D_DIM + d0 + lo;
      ob[off0] = acc0[r] + xb[off0] - cv[0][r];
      const size_t off1 = (size_t)(row + 32) * D_DIM + d0 + lo;
      ob[off1] = acc1[r] + xb[off1] - cv[1][r];
    }
  }
}

extern "C" void kernel_launch(void* const* d_in, const int* in_sizes, int n_in,
                              void* d_out, int out_size, void* d_ws,
                              size_t ws_size, hipStream_t stream) {
  const float* x = (const float*)d_in[0];
  float* out = (float*)d_out;
  char* ws = (char*)d_ws;

  float* Spart = (float*)ws;                            // 8 MB
  float* meanPart = (float*)(ws + 8388608);             // 128 KB
  float* Cout = (float*)(ws + 8519680);                 // 16 KB
  unsigned short* Mb = (unsigned short*)(ws + 8536064); // 512 KB

  k_cov_partial<<<dim3(SPLIT, B_DIM), 256, 0, stream>>>(x, Spart, meanPart);
  k_chol_inv<<<dim3(B_DIM), 64, 0, stream>>>(Spart, meanPart, Mb, Cout);
  k_whiten<<<dim3(D_DIM / 256, B_DIM), 256, 0, stream>>>(x, Cout, Mb, out);
}

// Round 8
// 169.203 us; speedup vs baseline: 1.0410x; 1.0410x over previous
//
#include <hip/hip_runtime.h>
#include <hip/hip_bf16.h>

typedef float f4vec  __attribute__((ext_vector_type(4)));
typedef float f16vec __attribute__((ext_vector_type(16)));
typedef short s8vec  __attribute__((ext_vector_type(8)));

#define B_DIM 64
#define N_DIM 64
#define D_DIM 9216
#define SPLIT 8
#define CHUNK 1152          // D_DIM / SPLIT
#define NSTEP (CHUNK / 64)  // 18

// ws layout (bytes):
//   Spart    @ 0        : 64*8*4096*4 = 8388608
//   meanPart @ 8388608  : 64*8*64*4   = 131072
//   Cout     @ 8519680  : 64*64*4     = 16384   (c = inv_L @ mean, fp32)
//   Mb(bf16) @ 8536064  : 64*4096*2   = 524288  (M = inv_L - I, row-major)

__device__ __forceinline__ short f2bf(float f) {
  union { __hip_bfloat16 h; short s; } u;
  u.h = __float2bfloat16(f);
  return u.s;
}

// v_readlane: static VGPR index, runtime-uniform (SGPR) lane index is legal.
__device__ __forceinline__ float rdlane(float v, int l) {
  union { float f; int i; } u;
  u.f = v;
  u.i = __builtin_amdgcn_readlane(u.i, l);
  return u.f;
}

// ---------------- Kernel 1: partial Gram + row-sum partials ----------------
__global__ __launch_bounds__(256) void k_cov_partial(
    const float* __restrict__ x, float* __restrict__ Spart,
    float* __restrict__ meanPart) {
  const int s = blockIdx.x, b = blockIdx.y;
  const int t = threadIdx.x;
  const int lane = t & 63, w = t >> 6;
  const int wr = w >> 1, wc = w & 1;
  const int hi = lane >> 5;

  __shared__ float T[64 * 64];

  const float* xb = x + (size_t)b * N_DIM * D_DIM + (size_t)s * CHUNK;
  const int jrow = t >> 2, q = t & 3;
  const float* xrow = xb + (size_t)jrow * D_DIM;

  f16vec acc;
#pragma unroll
  for (int r = 0; r < 16; ++r) acc[r] = 0.0f;
  float msum = 0.0f;

  const int r_a = 32 * wr + (lane & 31);
  const int r_b = 32 * wc + (lane & 31);

  f4vec v[4];
#pragma unroll
  for (int i = 0; i < 4; ++i)
    v[i] = *reinterpret_cast<const f4vec*>(xrow + (i * 4 + q) * 4);

  for (int step = 0; step < NSTEP; ++step) {
    __syncthreads();  // previous step's frag reads done; LDS free
#pragma unroll
    for (int i = 0; i < 4; ++i) {
      const int f = i * 4 + q;
      msum += v[i].x + v[i].y + v[i].z + v[i].w;
      *reinterpret_cast<f4vec*>(&T[jrow * 64 + ((f ^ (jrow & 15)) << 2)]) = v[i];
    }
    __syncthreads();  // tile ready
    if (step + 1 < NSTEP) {
      const float* xn = xrow + (step + 1) * 64;
#pragma unroll
      for (int i = 0; i < 4; ++i)
        v[i] = *reinterpret_cast<const f4vec*>(xn + (i * 4 + q) * 4);
    }
#pragma unroll
    for (int ks = 0; ks < 4; ++ks) {
      const int c0 = ks * 4 + hi * 2;
      f4vec a0 = *reinterpret_cast<const f4vec*>(
          &T[r_a * 64 + ((c0 ^ (r_a & 15)) << 2)]);
      f4vec a1 = *reinterpret_cast<const f4vec*>(
          &T[r_a * 64 + (((c0 + 1) ^ (r_a & 15)) << 2)]);
      f4vec b0 = *reinterpret_cast<const f4vec*>(
          &T[r_b * 64 + ((c0 ^ (r_b & 15)) << 2)]);
      f4vec b1 = *reinterpret_cast<const f4vec*>(
          &T[r_b * 64 + (((c0 + 1) ^ (r_b & 15)) << 2)]);
      s8vec af, bf;
      af[0]=f2bf(a0.x); af[1]=f2bf(a0.y); af[2]=f2bf(a0.z); af[3]=f2bf(a0.w);
      af[4]=f2bf(a1.x); af[5]=f2bf(a1.y); af[6]=f2bf(a1.z); af[7]=f2bf(a1.w);
      bf[0]=f2bf(b0.x); bf[1]=f2bf(b0.y); bf[2]=f2bf(b0.z); bf[3]=f2bf(b0.w);
      bf[4]=f2bf(b1.x); bf[5]=f2bf(b1.y); bf[6]=f2bf(b1.z); bf[7]=f2bf(b1.w);
      acc = __builtin_amdgcn_mfma_f32_32x32x16_bf16(af, bf, acc, 0, 0, 0);
    }
  }

  msum += __shfl_xor(msum, 1);
  msum += __shfl_xor(msum, 2);
  if (q == 0) meanPart[(b * SPLIT + s) * 64 + jrow] = msum;

  float* Sp = Spart + (size_t)(b * SPLIT + s) * 4096;
#pragma unroll
  for (int r = 0; r < 16; ++r) {
    const int i = 32 * wr + (r & 3) + 8 * (r >> 2) + 4 * hi;
    const int j = 32 * wc + (lane & 31);
    Sp[i * 64 + j] = acc[r];
  }
}

// ------- Kernel 2: Cholesky (registers) + fwd-sub inverse (LDS rows) -------
// One wave per block (one batch); lane i holds row i during Cholesky.
// Rounds 5-7 kept a[64]+y[64] live SIMULTANEOUSLY (~135 floats) -> allocator
// (targeting ~104 VGPRs) spilled state to scratch; every loop iteration was
// a scratch round-trip (116-126 us, VALUBusy 1.7%). Round-8 fix: phase
// split. Chol phase: only a[64] live (~75 floats, fits). Then dump A-bar to
// LDS ONCE (16.6 KB, pitch 65 -> 2-way bank alias, free) and a[] dies.
// Fwd-sub phase: only y[64] live (~75 floats, fits); row i of A-bar comes
// from BROADCAST LDS reads (all lanes same address: conflict-free, ~6 cyc,
// pipelined). No phase has >~80 live floats -> no scratch.
__global__ __launch_bounds__(64, 1) void k_chol_inv(
    const float* __restrict__ Spart, const float* __restrict__ meanPart,
    unsigned short* __restrict__ Mb, float* __restrict__ Cout) {
  const int lane = threadIdx.x;   // 0..63; lane i holds row i
  const int b = blockIdx.x;

  __shared__ float Ash[64 * 65];  // A-bar, row-major, pitch 65

  float mown = 0.0f;
#pragma unroll
  for (int p = 0; p < SPLIT; ++p)
    mown += meanPart[(b * SPLIT + p) * 64 + lane];
  mown *= (1.0f / D_DIM);

  float diag;     // own pivot d_lane (captured during chol)
  {
    float a[64];

    // Reduce 8 Gram partials for row `lane` (L2/L3-resident).
    const float* base = Spart + (size_t)(b * SPLIT) * 4096 + lane * 64;
#pragma unroll
    for (int j4 = 0; j4 < 16; ++j4) {
      f4vec s = *reinterpret_cast<const f4vec*>(base + j4 * 4);
#pragma unroll
      for (int p = 1; p < SPLIT; ++p)
        s += *reinterpret_cast<const f4vec*>(base + (size_t)p * 4096 + j4 * 4);
      a[j4 * 4 + 0] = s.x; a[j4 * 4 + 1] = s.y;
      a[j4 * 4 + 2] = s.z; a[j4 * 4 + 3] = s.w;
    }

    // cov[i][j] = (S[i][j] - D*m_i*m_j) / (D-1)
    {
      const float invD1 = 1.0f / (float)(D_DIM - 1);
      const float miD = mown * (float)D_DIM;
#pragma unroll
      for (int j = 0; j < 64; ++j)
        a[j] = (a[j] - miD * rdlane(mown, j)) * invD1;
    }

    // In-register right-looking Cholesky, unscaled pivots. m = pivot column
    // k (lane i's m = A[i][k]), maintained by an 8-wide cndmask capture
    // chain. Broadcast row k via trailing symmetry: A[k][j] = rdlane(m, j).
    float m = a[0];
#pragma clang loop unroll(disable)
    for (int k = 0; k < 64; ++k) {
      const float d = rdlane(m, k);                   // pivot d_k
      const float inv = __builtin_amdgcn_rcpf(d);
      const float f = (lane > k) ? m * inv : 0.0f;
#pragma unroll
      for (int jb = 0; jb < 8; ++jb) {
        if (jb * 8 + 8 > k) {              // block has some j > k (uniform)
          const bool mixed = (jb * 8 <= k);
#pragma unroll
          for (int jj = 0; jj < 8; ++jj) {
            const int j = jb * 8 + jj;
            const float bc = rdlane(m, j); // A[k][j] by trailing symmetry
            float upd = f * bc;
            if (mixed) upd = (j > k) ? upd : 0.0f;  // keep frozen part
            a[j] -= upd;
          }
        }
      }
      // Capture next pivot column m = a[k+1] (post-update). k=63: no-op.
#pragma unroll
      for (int jb = 0; jb < 8; ++jb) {
        if (((k + 1) >> 3) == jb) {
#pragma unroll
          for (int jj = 0; jj < 8; ++jj) {
            const int j = jb * 8 + jj;
            m = (j == k + 1) ? a[j] : m;
          }
        }
      }
    }

    // Capture own diagonal; dump A-bar row to LDS; a[] dies here.
    diag = 0.0f;
#pragma unroll
    for (int j = 0; j < 64; ++j) {
      diag = (j == lane) ? a[j] : diag;
      Ash[lane * 65 + j] = a[j];   // stride 65: 2 lanes/bank, free
    }
  }
  __builtin_amdgcn_s_waitcnt(0);   // lgkmcnt(0): LDS writes visible
  // (single wave: no barrier needed, wave-synchronous)

  const float sqd_own = __builtin_amdgcn_sqrtf(diag);

  // Forward substitution on A-bar; lane c owns column c of Y = inv(A-bar).
  // inv_L = diag(sqrt(d)) * Y. Row i of A-bar: broadcast LDS reads.
  float y[64];
#pragma unroll
  for (int j = 0; j < 64; ++j) y[j] = 0.0f;

  const size_t mb_base = (size_t)b * 4096;
#pragma clang loop unroll(disable)
  for (int i = 0; i < 64; ++i) {
    const float d = rdlane(diag, i);
    const float* arow = &Ash[i * 65];
    float s0 = 0.0f, s1 = 0.0f, s2 = 0.0f, s3 = 0.0f;
#pragma unroll
    for (int jb = 0; jb < 8; ++jb) {
      if (jb * 8 <= i) {                   // blocks fully above i: y==0
#pragma unroll
        for (int jj = 0; jj < 8; ++jj) {
          const int j = jb * 8 + jj;
          const float bc = arow[j];        // broadcast read, conflict-free
          const float pr = bc * y[j];
          if ((jj & 3) == 0) s0 += pr;
          else if ((jj & 3) == 1) s1 += pr;
          else if ((jj & 3) == 2) s2 += pr;
          else s3 += pr;
        }
      }
    }
    const float invd = __builtin_amdgcn_rcpf(d);
    const float del = (lane == i) ? 1.0f : 0.0f;
    const float yi = (del - ((s0 + s1) + (s2 + s3))) * invd;
    // y[i] = yi via 8-wide capture chain in the block containing i.
#pragma unroll
    for (int jb = 0; jb < 8; ++jb) {
      if ((i >> 3) == jb) {
#pragma unroll
        for (int jj = 0; jj < 8; ++jj) {
          const int j = jb * 8 + jj;
          y[j] = (j == i) ? yi : y[j];
        }
      }
    }
    const float xv = yi * __builtin_amdgcn_sqrtf(d);  // inv_L[i][lane]
    // M = inv_L - I, row i: coalesced u16 store.
    Mb[mb_base + i * 64 + lane] = (unsigned short)f2bf(xv - del);
  }

  // Cvec[i] = sqrt(d_i) * sum_c Y[i][c]*mean_c. 64 INDEPENDENT butterflies;
  // lane i ends holding S_i, scales by its own sqrt(diag), coalesced store.
  float res = 0.0f;
#pragma unroll
  for (int i = 0; i < 64; ++i) {
    float t2 = y[i] * mown;
    t2 += __shfl_xor(t2, 1);
    t2 += __shfl_xor(t2, 2);
    t2 += __shfl_xor(t2, 4);
    t2 += __shfl_xor(t2, 8);
    t2 += __shfl_xor(t2, 16);
    t2 += __shfl_xor(t2, 32);
    res = (lane == i) ? t2 : res;
  }
  Cout[b * 64 + lane] = res * sqd_own;
}

// ---------------- Kernel 3: out = x + M@x - c*1^T  (LDS-free) --------------
__global__ __launch_bounds__(256) void k_whiten(
    const float* __restrict__ x, const float* __restrict__ Cvec,
    const unsigned short* __restrict__ Mb, float* __restrict__ out) {
  const int b = blockIdx.y;
  const int t = threadIdx.x;
  const int wid = t >> 6, lane = t & 63;
  const int lo = lane & 31, hi = lane >> 5;

  s8vec mfrag[2][4];
  const unsigned short* Mbb = Mb + (size_t)b * 4096;
#pragma unroll
  for (int wr = 0; wr < 2; ++wr)
#pragma unroll
    for (int ks = 0; ks < 4; ++ks)
      mfrag[wr][ks] = *reinterpret_cast<const s8vec*>(
          Mbb + (32 * wr + lo) * 64 + ks * 16 + hi * 8);

  float cv[2][16];
  const float* cb = Cvec + b * 64;
#pragma unroll
  for (int wr = 0; wr < 2; ++wr)
#pragma unroll
    for (int r = 0; r < 16; ++r)
      cv[wr][r] = cb[32 * wr + (r & 3) + 8 * (r >> 2) + 4 * hi];

  const float* xb = x + (size_t)b * N_DIM * D_DIM;
  float* ob = out + (size_t)b * N_DIM * D_DIM;

#pragma unroll
  for (int n = 0; n < 2; ++n) {
    const int d0 = blockIdx.x * 256 + wid * 64 + n * 32;
    f16vec acc0, acc1;
#pragma unroll
    for (int r = 0; r < 16; ++r) { acc0[r] = 0.0f; acc1[r] = 0.0f; }

#pragma unroll
    for (int ks = 0; ks < 4; ++ks) {
      const float* colp = xb + (size_t)(16 * ks + 8 * hi) * D_DIM + d0 + lo;
      s8vec bf;
#pragma unroll
      for (int e = 0; e < 8; ++e) bf[e] = f2bf(colp[(size_t)e * D_DIM]);
      acc0 = __builtin_amdgcn_mfma_f32_32x32x16_bf16(mfrag[0][ks], bf, acc0, 0, 0, 0);
      acc1 = __builtin_amdgcn_mfma_f32_32x32x16_bf16(mfrag[1][ks], bf, acc1, 0, 0, 0);
    }

#pragma unroll
    for (int r = 0; r < 16; ++r) {
      const int row = (r & 3) + 8 * (r >> 2) + 4 * hi;
      const size_t off0 = (size_t)row * D_DIM + d0 + lo;
      ob[off0] = acc0[r] + xb[off0] - cv[0][r];
      const size_t off1 = (size_t)(row + 32) * D_DIM + d0 + lo;
      ob[off1] = acc1[r] + xb[off1] - cv[1][r];
    }
  }
}

extern "C" void kernel_launch(void* const* d_in, const int* in_sizes, int n_in,
                              void* d_out, int out_size, void* d_ws,
                              size_t ws_size, hipStream_t stream) {
  const float* x = (const float*)d_in[0];
  float* out = (float*)d_out;
  char* ws = (char*)d_ws;

  float* Spart = (float*)ws;                            // 8 MB
  float* meanPart = (float*)(ws + 8388608);             // 128 KB
  float* Cout = (float*)(ws + 8519680);                 // 16 KB
  unsigned short* Mb = (unsigned short*)(ws + 8536064); // 512 KB

  k_cov_partial<<<dim3(SPLIT, B_DIM), 256, 0, stream>>>(x, Spart, meanPart);
  k_chol_inv<<<dim3(B_DIM), 64, 0, stream>>>(Spart, meanPart, Mb, Cout);
  k_whiten<<<dim3(D_DIM / 256, B_DIM), 256, 0, stream>>>(x, Cout, Mb, out);
}

// Round 9
// 134.345 us; speedup vs baseline: 1.3112x; 1.2595x over previous
//
#include <hip/hip_runtime.h>
#include <hip/hip_bf16.h>

typedef float f4vec  __attribute__((ext_vector_type(4)));
typedef float f16vec __attribute__((ext_vector_type(16)));
typedef short s8vec  __attribute__((ext_vector_type(8)));

#define B_DIM 64
#define N_DIM 64
#define D_DIM 9216
#define SPLIT 8
#define CHUNK 1152          // D_DIM / SPLIT
#define NSTEP (CHUNK / 64)  // 18

// ws layout (bytes):
//   Spart    @ 0        : 64*8*4096*4 = 8388608
//   meanPart @ 8388608  : 64*8*64*4   = 131072
//   Cout     @ 8519680  : 64*64*4     = 16384   (c = inv_L @ mean, fp32)
//   Mb(bf16) @ 8536064  : 64*4096*2   = 524288  (M = inv_L - I, row-major)

__device__ __forceinline__ short f2bf(float f) {
  union { __hip_bfloat16 h; short s; } u;
  u.h = __float2bfloat16(f);
  return u.s;
}

// ---------------- Kernel 1: partial Gram + row-sum partials ----------------
__global__ __launch_bounds__(256) void k_cov_partial(
    const float* __restrict__ x, float* __restrict__ Spart,
    float* __restrict__ meanPart) {
  const int s = blockIdx.x, b = blockIdx.y;
  const int t = threadIdx.x;
  const int lane = t & 63, w = t >> 6;
  const int wr = w >> 1, wc = w & 1;
  const int hi = lane >> 5;

  __shared__ float T[64 * 64];

  const float* xb = x + (size_t)b * N_DIM * D_DIM + (size_t)s * CHUNK;
  const int jrow = t >> 2, q = t & 3;
  const float* xrow = xb + (size_t)jrow * D_DIM;

  f16vec acc;
#pragma unroll
  for (int r = 0; r < 16; ++r) acc[r] = 0.0f;
  float msum = 0.0f;

  const int r_a = 32 * wr + (lane & 31);
  const int r_b = 32 * wc + (lane & 31);

  f4vec v[4];
#pragma unroll
  for (int i = 0; i < 4; ++i)
    v[i] = *reinterpret_cast<const f4vec*>(xrow + (i * 4 + q) * 4);

  for (int step = 0; step < NSTEP; ++step) {
    __syncthreads();  // previous step's frag reads done; LDS free
#pragma unroll
    for (int i = 0; i < 4; ++i) {
      const int f = i * 4 + q;
      msum += v[i].x + v[i].y + v[i].z + v[i].w;
      *reinterpret_cast<f4vec*>(&T[jrow * 64 + ((f ^ (jrow & 15)) << 2)]) = v[i];
    }
    __syncthreads();  // tile ready
    if (step + 1 < NSTEP) {
      const float* xn = xrow + (step + 1) * 64;
#pragma unroll
      for (int i = 0; i < 4; ++i)
        v[i] = *reinterpret_cast<const f4vec*>(xn + (i * 4 + q) * 4);
    }
#pragma unroll
    for (int ks = 0; ks < 4; ++ks) {
      const int c0 = ks * 4 + hi * 2;
      f4vec a0 = *reinterpret_cast<const f4vec*>(
          &T[r_a * 64 + ((c0 ^ (r_a & 15)) << 2)]);
      f4vec a1 = *reinterpret_cast<const f4vec*>(
          &T[r_a * 64 + (((c0 + 1) ^ (r_a & 15)) << 2)]);
      f4vec b0 = *reinterpret_cast<const f4vec*>(
          &T[r_b * 64 + ((c0 ^ (r_b & 15)) << 2)]);
      f4vec b1 = *reinterpret_cast<const f4vec*>(
          &T[r_b * 64 + (((c0 + 1) ^ (r_b & 15)) << 2)]);
      s8vec af, bf;
      af[0]=f2bf(a0.x); af[1]=f2bf(a0.y); af[2]=f2bf(a0.z); af[3]=f2bf(a0.w);
      af[4]=f2bf(a1.x); af[5]=f2bf(a1.y); af[6]=f2bf(a1.z); af[7]=f2bf(a1.w);
      bf[0]=f2bf(b0.x); bf[1]=f2bf(b0.y); bf[2]=f2bf(b0.z); bf[3]=f2bf(b0.w);
      bf[4]=f2bf(b1.x); bf[5]=f2bf(b1.y); bf[6]=f2bf(b1.z); bf[7]=f2bf(b1.w);
      acc = __builtin_amdgcn_mfma_f32_32x32x16_bf16(af, bf, acc, 0, 0, 0);
    }
  }

  msum += __shfl_xor(msum, 1);
  msum += __shfl_xor(msum, 2);
  if (q == 0) meanPart[(b * SPLIT + s) * 64 + jrow] = msum;

  float* Sp = Spart + (size_t)(b * SPLIT + s) * 4096;
#pragma unroll
  for (int r = 0; r < 16; ++r) {
    const int i = 32 * wr + (r & 3) + 8 * (r >> 2) + 4 * hi;
    const int j = 32 * wc + (lane & 31);
    Sp[i * 64 + j] = acc[r];
  }
}

// ------- Kernel 2: cooperative 256-thread Cholesky + fwd-sub inverse -------
// Rounds 5-8 proved the 1-wave-per-batch version is pinned at ~115 us by its
// own serial critical path (~21K instrs x ~13 cyc of exposed latency; no
// co-resident TLP can hide it, and wall time = one wave's latency). Fix:
// parallelize each batch across 256 threads.
//  - Cholesky keeps the FULL SYMMETRIC matrix in LDS (the outer-product
//    update preserves symmetry), unscaled pivots: at step k only frozen
//    row/col k are read -> ONE barrier per step. Thread t owns 16 elements
//    of row (t>>2): ~12 LDS ops + ~40 VALU per step, all independent.
//  - Fwd-sub has ZERO barriers: columns independent; 4 same-wave lanes per
//    column; y in registers (16 slots/lane, cndmask capture with
//    compile-time indices); row i of A-bar via BROADCAST LDS reads
//    (address independent of column). Upper-triangle zeros are exact
//    (yreg starts 0), so the dot product needs no guards.
// Pitch 68 floats: f4 rows stay 16B-aligned.
__global__ __launch_bounds__(256) void k_chol_inv(
    const float* __restrict__ Spart, const float* __restrict__ meanPart,
    unsigned short* __restrict__ Mb, float* __restrict__ Cout) {
  const int t = threadIdx.x;
  const int b = blockIdx.x;

  __shared__ float Ash[64 * 68];
  __shared__ float Ysh[64 * 68];
  __shared__ float mean_sh[64];

  // mean[c] = (1/D) * sum_p meanPart
  if (t < 64) {
    float mm = 0.0f;
#pragma unroll
    for (int p = 0; p < SPLIT; ++p) mm += meanPart[(b * SPLIT + p) * 64 + t];
    mean_sh[t] = mm * (1.0f / D_DIM);
  }
  __syncthreads();

  // cov reduce: thread t handles f4-chunks f = t + 256*m (coalesced loads).
  {
    const float invD1 = 1.0f / (float)(D_DIM - 1);
    const f4vec* Sp =
        reinterpret_cast<const f4vec*>(Spart + (size_t)(b * SPLIT) * 4096);
#pragma unroll
    for (int m = 0; m < 4; ++m) {
      const int f = t + 256 * m;
      f4vec s = Sp[f];
#pragma unroll
      for (int p = 1; p < SPLIT; ++p) s += Sp[p * 1024 + f];
      const int row = f >> 4, c4 = f & 15;
      const float miD = mean_sh[row] * (float)D_DIM;
      const f4vec mj = *reinterpret_cast<const f4vec*>(&mean_sh[c4 * 4]);
      f4vec r;
      r.x = (s.x - miD * mj.x) * invD1;
      r.y = (s.y - miD * mj.y) * invD1;
      r.z = (s.z - miD * mj.z) * invD1;
      r.w = (s.w - miD * mj.w) * invD1;
      *reinterpret_cast<f4vec*>(&Ash[row * 68 + c4 * 4]) = r;
    }
  }
  __syncthreads();

  // Cholesky, unscaled pivots, full symmetric update, 1 barrier/step.
  // Thread: row ci = t>>2, j-range [jq, jq+16).
  const int ci = t >> 2, jq = (t & 3) * 16;
#pragma clang loop unroll(disable)
  for (int k = 0; k < 64; ++k) {
    const float dk = Ash[k * 68 + k];               // broadcast read
    const float inv = __builtin_amdgcn_rcpf(dk);
    if (ci > k && jq + 16 > k) {
      const float fik = Ash[ci * 68 + k] * inv;     // frozen col k
#pragma unroll
      for (int m = 0; m < 4; ++m) {
        const int j = jq + m * 4;
        f4vec o  = *reinterpret_cast<const f4vec*>(&Ash[ci * 68 + j]);
        f4vec rk = *reinterpret_cast<const f4vec*>(&Ash[k * 68 + j]);
        f4vec nv;
        nv.x = (j + 0 > k) ? o.x - fik * rk.x : o.x;
        nv.y = (j + 1 > k) ? o.y - fik * rk.y : o.y;
        nv.z = (j + 2 > k) ? o.z - fik * rk.z : o.z;
        nv.w = (j + 3 > k) ? o.w - fik * rk.w : o.w;
        *reinterpret_cast<f4vec*>(&Ash[ci * 68 + j]) = nv;
      }
    }
    __syncthreads();
  }

  // Forward substitution: column c = t>>2, sub-lane g = t&3 owns slots
  // j = g + 4s. Zero barriers (A-bar frozen; y private to 4 same-wave lanes).
  const int c = t >> 2, g = t & 3;
  float yreg[16];
#pragma unroll
  for (int s2 = 0; s2 < 16; ++s2) yreg[s2] = 0.0f;

  const size_t mb_base = (size_t)b * 4096;
#pragma clang loop unroll(disable)
  for (int i = 0; i < 64; ++i) {
    const float di = Ash[i * 68 + i];               // broadcast
    float part = 0.0f;
#pragma unroll
    for (int s2 = 0; s2 < 16; ++s2) {
      // Ash[i][g+4*s2]: address independent of c -> broadcast read.
      part += Ash[i * 68 + g + 4 * s2] * yreg[s2];  // y=0 above i: exact
    }
    part += __shfl_xor(part, 1);
    part += __shfl_xor(part, 2);
    const float del = (c == i) ? 1.0f : 0.0f;
    const float yi = (del - part) * __builtin_amdgcn_rcpf(di);
    // capture into slot i>>2 of the g == (i&3) sub-lane (static indices)
#pragma unroll
    for (int s2 = 0; s2 < 16; ++s2)
      yreg[s2] = (s2 == (i >> 2) && g == (i & 3)) ? yi : yreg[s2];
    if (g == (i & 3)) {
      const float xv = yi * __builtin_amdgcn_sqrtf(di);  // inv_L[i][c]
      Mb[mb_base + i * 64 + c] = (unsigned short)f2bf(xv - del);
      Ysh[i * 68 + c] = yi;
    }
  }
  __syncthreads();

  // Cvec[i] = sqrt(d_i) * sum_c Y[i][c]*mean[c]
  {
    const int i2 = t >> 2;
    float p2 = 0.0f;
#pragma unroll
    for (int s2 = 0; s2 < 16; ++s2) {
      const int cc = g + 4 * s2;
      p2 += Ysh[i2 * 68 + cc] * mean_sh[cc];
    }
    p2 += __shfl_xor(p2, 1);
    p2 += __shfl_xor(p2, 2);
    if (g == 0)
      Cout[b * 64 + i2] = p2 * __builtin_amdgcn_sqrtf(Ash[i2 * 68 + i2]);
  }
}

// ---------------- Kernel 3: out = x + M@x - c*1^T  (LDS-free) --------------
__global__ __launch_bounds__(256) void k_whiten(
    const float* __restrict__ x, const float* __restrict__ Cvec,
    const unsigned short* __restrict__ Mb, float* __restrict__ out) {
  const int b = blockIdx.y;
  const int t = threadIdx.x;
  const int wid = t >> 6, lane = t & 63;
  const int lo = lane & 31, hi = lane >> 5;

  s8vec mfrag[2][4];
  const unsigned short* Mbb = Mb + (size_t)b * 4096;
#pragma unroll
  for (int wr = 0; wr < 2; ++wr)
#pragma unroll
    for (int ks = 0; ks < 4; ++ks)
      mfrag[wr][ks] = *reinterpret_cast<const s8vec*>(
          Mbb + (32 * wr + lo) * 64 + ks * 16 + hi * 8);

  float cv[2][16];
  const float* cb = Cvec + b * 64;
#pragma unroll
  for (int wr = 0; wr < 2; ++wr)
#pragma unroll
    for (int r = 0; r < 16; ++r)
      cv[wr][r] = cb[32 * wr + (r & 3) + 8 * (r >> 2) + 4 * hi];

  const float* xb = x + (size_t)b * N_DIM * D_DIM;
  float* ob = out + (size_t)b * N_DIM * D_DIM;

#pragma unroll
  for (int n = 0; n < 2; ++n) {
    const int d0 = blockIdx.x * 256 + wid * 64 + n * 32;
    f16vec acc0, acc1;
#pragma unroll
    for (int r = 0; r < 16; ++r) { acc0[r] = 0.0f; acc1[r] = 0.0f; }

#pragma unroll
    for (int ks = 0; ks < 4; ++ks) {
      const float* colp = xb + (size_t)(16 * ks + 8 * hi) * D_DIM + d0 + lo;
      s8vec bf;
#pragma unroll
      for (int e = 0; e < 8; ++e) bf[e] = f2bf(colp[(size_t)e * D_DIM]);
      acc0 = __builtin_amdgcn_mfma_f32_32x32x16_bf16(mfrag[0][ks], bf, acc0, 0, 0, 0);
      acc1 = __builtin_amdgcn_mfma_f32_32x32x16_bf16(mfrag[1][ks], bf, acc1, 0, 0, 0);
    }

#pragma unroll
    for (int r = 0; r < 16; ++r) {
      const int row = (r & 3) + 8 * (r >> 2) + 4 * hi;
      const size_t off0 = (size_t)row * D_DIM + d0 + lo;
      ob[off0] = acc0[r] + xb[off0] - cv[0][r];
      const size_t off1 = (size_t)(row + 32) * D_DIM + d0 + lo;
      ob[off1] = acc1[r] + xb[off1] - cv[1][r];
    }
  }
}

extern "C" void kernel_launch(void* const* d_in, const int* in_sizes, int n_in,
                              void* d_out, int out_size, void* d_ws,
                              size_t ws_size, hipStream_t stream) {
  const float* x = (const float*)d_in[0];
  float* out = (float*)d_out;
  char* ws = (char*)d_ws;

  float* Spart = (float*)ws;                            // 8 MB
  float* meanPart = (float*)(ws + 8388608);             // 128 KB
  float* Cout = (float*)(ws + 8519680);                 // 16 KB
  unsigned short* Mb = (unsigned short*)(ws + 8536064); // 512 KB

  k_cov_partial<<<dim3(SPLIT, B_DIM), 256, 0, stream>>>(x, Spart, meanPart);
  k_chol_inv<<<dim3(B_DIM), 256, 0, stream>>>(Spart, meanPart, Mb, Cout);
  k_whiten<<<dim3(D_DIM / 256, B_DIM), 256, 0, stream>>>(x, Cout, Mb, out);
}

// Round 10
// 119.031 us; speedup vs baseline: 1.4798x; 1.1287x over previous
//
#include <hip/hip_runtime.h>
#include <hip/hip_bf16.h>

typedef float f4vec  __attribute__((ext_vector_type(4)));
typedef float f16vec __attribute__((ext_vector_type(16)));
typedef short s8vec  __attribute__((ext_vector_type(8)));

#define B_DIM 64
#define N_DIM 64
#define D_DIM 9216
#define SPLIT 8
#define CHUNK 1152          // D_DIM / SPLIT
#define NSTEP (CHUNK / 64)  // 18

// ws layout (bytes):
//   Spart    @ 0        : 64*8*4096*4 = 8388608
//   meanPart @ 8388608  : 64*8*64*4   = 131072
//   Cout     @ 8519680  : 64*64*4     = 16384   (c = inv_L @ mean, fp32)
//   Mb(bf16) @ 8536064  : 64*4096*2   = 524288  (M = inv_L - I, row-major)

__device__ __forceinline__ short f2bf(float f) {
  union { __hip_bfloat16 h; short s; } u;
  u.h = __float2bfloat16(f);
  return u.s;
}

// v_readlane: static VGPR, runtime-uniform (SGPR) lane index is legal.
__device__ __forceinline__ float rdlane(float v, int l) {
  union { float f; int i; } u;
  u.f = v;
  u.i = __builtin_amdgcn_readlane(u.i, l);
  return u.f;
}

// ---------------- Kernel 1: partial Gram + row-sum partials ----------------
__global__ __launch_bounds__(256) void k_cov_partial(
    const float* __restrict__ x, float* __restrict__ Spart,
    float* __restrict__ meanPart) {
  const int s = blockIdx.x, b = blockIdx.y;
  const int t = threadIdx.x;
  const int lane = t & 63, w = t >> 6;
  const int wr = w >> 1, wc = w & 1;
  const int hi = lane >> 5;

  __shared__ float T[64 * 64];

  const float* xb = x + (size_t)b * N_DIM * D_DIM + (size_t)s * CHUNK;
  const int jrow = t >> 2, q = t & 3;
  const float* xrow = xb + (size_t)jrow * D_DIM;

  f16vec acc;
#pragma unroll
  for (int r = 0; r < 16; ++r) acc[r] = 0.0f;
  float msum = 0.0f;

  const int r_a = 32 * wr + (lane & 31);
  const int r_b = 32 * wc + (lane & 31);

  f4vec v[4];
#pragma unroll
  for (int i = 0; i < 4; ++i)
    v[i] = *reinterpret_cast<const f4vec*>(xrow + (i * 4 + q) * 4);

  for (int step = 0; step < NSTEP; ++step) {
    __syncthreads();  // previous step's frag reads done; LDS free
#pragma unroll
    for (int i = 0; i < 4; ++i) {
      const int f = i * 4 + q;
      msum += v[i].x + v[i].y + v[i].z + v[i].w;
      *reinterpret_cast<f4vec*>(&T[jrow * 64 + ((f ^ (jrow & 15)) << 2)]) = v[i];
    }
    __syncthreads();  // tile ready
    if (step + 1 < NSTEP) {
      const float* xn = xrow + (step + 1) * 64;
#pragma unroll
      for (int i = 0; i < 4; ++i)
        v[i] = *reinterpret_cast<const f4vec*>(xn + (i * 4 + q) * 4);
    }
#pragma unroll
    for (int ks = 0; ks < 4; ++ks) {
      const int c0 = ks * 4 + hi * 2;
      f4vec a0 = *reinterpret_cast<const f4vec*>(
          &T[r_a * 64 + ((c0 ^ (r_a & 15)) << 2)]);
      f4vec a1 = *reinterpret_cast<const f4vec*>(
          &T[r_a * 64 + (((c0 + 1) ^ (r_a & 15)) << 2)]);
      f4vec b0 = *reinterpret_cast<const f4vec*>(
          &T[r_b * 64 + ((c0 ^ (r_b & 15)) << 2)]);
      f4vec b1 = *reinterpret_cast<const f4vec*>(
          &T[r_b * 64 + (((c0 + 1) ^ (r_b & 15)) << 2)]);
      s8vec af, bf;
      af[0]=f2bf(a0.x); af[1]=f2bf(a0.y); af[2]=f2bf(a0.z); af[3]=f2bf(a0.w);
      af[4]=f2bf(a1.x); af[5]=f2bf(a1.y); af[6]=f2bf(a1.z); af[7]=f2bf(a1.w);
      bf[0]=f2bf(b0.x); bf[1]=f2bf(b0.y); bf[2]=f2bf(b0.z); bf[3]=f2bf(b0.w);
      bf[4]=f2bf(b1.x); bf[5]=f2bf(b1.y); bf[6]=f2bf(b1.z); bf[7]=f2bf(b1.w);
      acc = __builtin_amdgcn_mfma_f32_32x32x16_bf16(af, bf, acc, 0, 0, 0);
    }
  }

  msum += __shfl_xor(msum, 1);
  msum += __shfl_xor(msum, 2);
  if (q == 0) meanPart[(b * SPLIT + s) * 64 + jrow] = msum;

  float* Sp = Spart + (size_t)(b * SPLIT + s) * 4096;
#pragma unroll
  for (int r = 0; r < 16; ++r) {
    const int i = 32 * wr + (r & 3) + 8 * (r >> 2) + 4 * hi;
    const int j = 32 * wc + (lane & 31);
    Sp[i * 64 + j] = acc[r];
  }
}

// ------ Kernel 2: blocked cooperative Cholesky + pipelined fwd-sub ---------
// r2/r9 both pinned at ~80-85 us by 128 serial steps of exposed LDS/barrier
// latency (~1.5K cyc/step). r10: cut chol to 8 outer steps (rank-8 panels;
// panel factored REDUNDANTLY by all 4 waves in registers, lane = row ->
// the pivot chain is register readlane+fma, no LDS/barrier per pivot;
// trailing update rank-8 per barrier). Fwd-sub: f4 broadcast loads (4 vs 16),
// 4-way split FMA chains, 2-stage row prefetch; y in registers; 0 barriers.
__global__ __launch_bounds__(256) void k_chol_inv(
    const float* __restrict__ Spart, const float* __restrict__ meanPart,
    unsigned short* __restrict__ Mb, float* __restrict__ Cout) {
  const int t = threadIdx.x;
  const int b = blockIdx.x;
  const int wid = t >> 6, lane = t & 63;

  __shared__ float Ash[64 * 68];   // pitch 68: f4-aligned, odd f4-stride (17)
  __shared__ float Ysh[64 * 68];
  __shared__ float mean_sh[64];

  if (t < 64) {
    float mm = 0.0f;
#pragma unroll
    for (int p = 0; p < SPLIT; ++p) mm += meanPart[(b * SPLIT + p) * 64 + t];
    mean_sh[t] = mm * (1.0f / D_DIM);
  }
  __syncthreads();

  // cov reduce: thread t handles f4-chunks f = t + 256*m (coalesced loads).
  {
    const float invD1 = 1.0f / (float)(D_DIM - 1);
    const f4vec* Sp =
        reinterpret_cast<const f4vec*>(Spart + (size_t)(b * SPLIT) * 4096);
#pragma unroll
    for (int m = 0; m < 4; ++m) {
      const int f = t + 256 * m;
      f4vec s = Sp[f];
#pragma unroll
      for (int p = 1; p < SPLIT; ++p) s += Sp[p * 1024 + f];
      const int row = f >> 4, c4 = f & 15;
      const float miD = mean_sh[row] * (float)D_DIM;
      const f4vec mj = *reinterpret_cast<const f4vec*>(&mean_sh[c4 * 4]);
      f4vec r;
      r.x = (s.x - miD * mj.x) * invD1;
      r.y = (s.y - miD * mj.y) * invD1;
      r.z = (s.z - miD * mj.z) * invD1;
      r.w = (s.w - miD * mj.w) * invD1;
      *reinterpret_cast<f4vec*>(&Ash[row * 68 + c4 * 4]) = r;
    }
  }
  __syncthreads();

  // ---- Blocked Cholesky: 8 panels x 8 cols; ONE barrier per panel. ----
  // Unscaled pivots (A-bar[i][j] = L[i][j]*sqrt(d_j), diag d). Trailing
  // uses symmetry: A22[i][j] -= sum_c fl[i][c] * p[j][c].
#pragma clang loop unroll(disable)
  for (int kb = 0; kb < 8; ++kb) {
    const int K = kb * 8;
    // 1. all waves load panel cols K..K+7 for own row `lane` (2 f4 reads)
    float p[8];
    {
      f4vec pa = *reinterpret_cast<const f4vec*>(&Ash[lane * 68 + K]);
      f4vec pb = *reinterpret_cast<const f4vec*>(&Ash[lane * 68 + K + 4]);
      p[0]=pa.x; p[1]=pa.y; p[2]=pa.z; p[3]=pa.w;
      p[4]=pb.x; p[5]=pb.y; p[6]=pb.z; p[7]=pb.w;
    }
    // 2. factor panel in registers (redundant in all 4 waves)
    float fl[8];
#pragma unroll
    for (int c = 0; c < 8; ++c) {
      const int kc = K + c;
      const float d = rdlane(p[c], kc);
      const float inv = __builtin_amdgcn_rcpf(d);
      const float f = (lane > kc) ? p[c] * inv : 0.0f;
      fl[c] = f;
#pragma unroll
      for (int j = c + 1; j < 8; ++j)
        p[j] -= f * rdlane(p[j], kc);
    }
    // 3. owning wave writes factored panel back
    if (wid == (kb >> 1)) {
      f4vec pa, pb;
      pa.x=p[0]; pa.y=p[1]; pa.z=p[2]; pa.w=p[3];
      pb.x=p[4]; pb.y=p[5]; pb.z=p[6]; pb.w=p[7];
      *reinterpret_cast<f4vec*>(&Ash[lane * 68 + K]) = pa;
      *reinterpret_cast<f4vec*>(&Ash[lane * 68 + K + 4]) = pb;
    }
    // 4. trailing rank-8 update: wave owns 16 cols (4 f4-quads); quads with
    //    start >= K+8 only (K+8 is 4-aligned). fl==0 for rows <= pivot ->
    //    frozen rows rewritten unchanged (benign, race-free: (row,col)
    //    ownership is (lane, wave) unique).
#pragma unroll
    for (int q = 0; q < 4; ++q) {
      const int j0 = 16 * wid + 4 * q;
      if (j0 >= K + 8) {                      // wave-uniform branch
        f4vec o = *reinterpret_cast<const f4vec*>(&Ash[lane * 68 + j0]);
        float sx = 0.0f, sy = 0.0f, sz = 0.0f, sw = 0.0f;
#pragma unroll
        for (int c = 0; c < 8; ++c) {
          sx += fl[c] * rdlane(p[c], j0 + 0);
          sy += fl[c] * rdlane(p[c], j0 + 1);
          sz += fl[c] * rdlane(p[c], j0 + 2);
          sw += fl[c] * rdlane(p[c], j0 + 3);
        }
        o.x -= sx; o.y -= sy; o.z -= sz; o.w -= sw;
        *reinterpret_cast<f4vec*>(&Ash[lane * 68 + j0]) = o;
      }
    }
    __syncthreads();
  }

  // ---- Fwd-sub: column c = t>>2, sub-lane g = t&3 owns y slots
  //      j = 16g..16g+15. Zero barriers; 2-stage row prefetch. ----
  const int c = t >> 2, g = t & 3;
  const int jbase = g * 16;
  float yreg[16];
#pragma unroll
  for (int s2 = 0; s2 < 16; ++s2) yreg[s2] = 0.0f;

  const size_t mb_base = (size_t)b * 4096;

  f4vec cur[4];
  float dcur;
  {
    const float* r0 = &Ash[jbase];
#pragma unroll
    for (int m = 0; m < 4; ++m)
      cur[m] = *reinterpret_cast<const f4vec*>(r0 + 4 * m);
    dcur = Ash[0];
  }
#pragma clang loop unroll(disable)
  for (int i = 0; i < 64; ++i) {
    // prefetch row i+1 (broadcast f4 reads; compiler's counted lgkmcnt
    // keeps them in flight across the compute below)
    const int ip = (i < 63) ? i + 1 : 63;
    f4vec nxt[4];
    const float* rn = &Ash[ip * 68 + jbase];
#pragma unroll
    for (int m = 0; m < 4; ++m)
      nxt[m] = *reinterpret_cast<const f4vec*>(rn + 4 * m);
    const float dn = Ash[ip * 68 + ip];

    // dot: 4 independent chains (y=0 for slots >= i -> stale upper exact 0)
    const float p0 = ((cur[0].x * yreg[0] + cur[0].y * yreg[1]) +
                      (cur[0].z * yreg[2] + cur[0].w * yreg[3]));
    const float p1 = ((cur[1].x * yreg[4] + cur[1].y * yreg[5]) +
                      (cur[1].z * yreg[6] + cur[1].w * yreg[7]));
    const float p2 = ((cur[2].x * yreg[8] + cur[2].y * yreg[9]) +
                      (cur[2].z * yreg[10] + cur[2].w * yreg[11]));
    const float p3 = ((cur[3].x * yreg[12] + cur[3].y * yreg[13]) +
                      (cur[3].z * yreg[14] + cur[3].w * yreg[15]));
    float part = (p0 + p1) + (p2 + p3);
    part += __shfl_xor(part, 1);
    part += __shfl_xor(part, 2);
    const float del = (c == i) ? 1.0f : 0.0f;
    const float yi = (del - part) * __builtin_amdgcn_rcpf(dcur);
    // capture y_i into its slot (static reg indices, runtime compare)
#pragma unroll
    for (int s2 = 0; s2 < 16; ++s2)
      yreg[s2] = (jbase + s2 == i) ? yi : yreg[s2];
    if (g == (i & 3)) {   // one of the 4 sub-lanes stores
      const float xv = yi * __builtin_amdgcn_sqrtf(dcur);  // inv_L[i][c]
      Mb[mb_base + i * 64 + c] = (unsigned short)f2bf(xv - del);
      Ysh[i * 68 + c] = yi;
    }
#pragma unroll
    for (int m = 0; m < 4; ++m) cur[m] = nxt[m];
    dcur = dn;
  }
  __syncthreads();

  // Cvec[i] = sqrt(d_i) * sum_c Y[i][c]*mean[c]
  {
    const int i2 = t >> 2;
    float pz = 0.0f;
#pragma unroll
    for (int s2 = 0; s2 < 16; ++s2) {
      const int cc = g + 4 * s2;
      pz += Ysh[i2 * 68 + cc] * mean_sh[cc];
    }
    pz += __shfl_xor(pz, 1);
    pz += __shfl_xor(pz, 2);
    if (g == 0)
      Cout[b * 64 + i2] = pz * __builtin_amdgcn_sqrtf(Ash[i2 * 68 + i2]);
  }
}

// ---------------- Kernel 3: out = x + M@x - c*1^T  (LDS-free) --------------
__global__ __launch_bounds__(256) void k_whiten(
    const float* __restrict__ x, const float* __restrict__ Cvec,
    const unsigned short* __restrict__ Mb, float* __restrict__ out) {
  const int b = blockIdx.y;
  const int t = threadIdx.x;
  const int wid = t >> 6, lane = t & 63;
  const int lo = lane & 31, hi = lane >> 5;

  s8vec mfrag[2][4];
  const unsigned short* Mbb = Mb + (size_t)b * 4096;
#pragma unroll
  for (int wr = 0; wr < 2; ++wr)
#pragma unroll
    for (int ks = 0; ks < 4; ++ks)
      mfrag[wr][ks] = *reinterpret_cast<const s8vec*>(
          Mbb + (32 * wr + lo) * 64 + ks * 16 + hi * 8);

  float cv[2][16];
  const float* cb = Cvec + b * 64;
#pragma unroll
  for (int wr = 0; wr < 2; ++wr)
#pragma unroll
    for (int r = 0; r < 16; ++r)
      cv[wr][r] = cb[32 * wr + (r & 3) + 8 * (r >> 2) + 4 * hi];

  const float* xb = x + (size_t)b * N_DIM * D_DIM;
  float* ob = out + (size_t)b * N_DIM * D_DIM;

#pragma unroll
  for (int n = 0; n < 2; ++n) {
    const int d0 = blockIdx.x * 256 + wid * 64 + n * 32;
    f16vec acc0, acc1;
#pragma unroll
    for (int r = 0; r < 16; ++r) { acc0[r] = 0.0f; acc1[r] = 0.0f; }

#pragma unroll
    for (int ks = 0; ks < 4; ++ks) {
      const float* colp = xb + (size_t)(16 * ks + 8 * hi) * D_DIM + d0 + lo;
      s8vec bf;
#pragma unroll
      for (int e = 0; e < 8; ++e) bf[e] = f2bf(colp[(size_t)e * D_DIM]);
      acc0 = __builtin_amdgcn_mfma_f32_32x32x16_bf16(mfrag[0][ks], bf, acc0, 0, 0, 0);
      acc1 = __builtin_amdgcn_mfma_f32_32x32x16_bf16(mfrag[1][ks], bf, acc1, 0, 0, 0);
    }

#pragma unroll
    for (int r = 0; r < 16; ++r) {
      const int row = (r & 3) + 8 * (r >> 2) + 4 * hi;
      const size_t off0 = (size_t)row * D_DIM + d0 + lo;
      ob[off0] = acc0[r] + xb[off0] - cv[0][r];
      const size_t off1 = (size_t)(row + 32) * D_DIM + d0 + lo;
      ob[off1] = acc1[r] + xb[off1] - cv[1][r];
    }
  }
}

extern "C" void kernel_launch(void* const* d_in, const int* in_sizes, int n_in,
                              void* d_out, int out_size, void* d_ws,
                              size_t ws_size, hipStream_t stream) {
  const float* x = (const float*)d_in[0];
  float* out = (float*)d_out;
  char* ws = (char*)d_ws;

  float* Spart = (float*)ws;                            // 8 MB
  float* meanPart = (float*)(ws + 8388608);             // 128 KB
  float* Cout = (float*)(ws + 8519680);                 // 16 KB
  unsigned short* Mb = (unsigned short*)(ws + 8536064); // 512 KB

  k_cov_partial<<<dim3(SPLIT, B_DIM), 256, 0, stream>>>(x, Spart, meanPart);
  k_chol_inv<<<dim3(B_DIM), 256, 0, stream>>>(Spart, meanPart, Mb, Cout);
  k_whiten<<<dim3(D_DIM / 256, B_DIM), 256, 0, stream>>>(x, Cout, Mb, out);
}

// Round 11
// 101.586 us; speedup vs baseline: 1.7340x; 1.1717x over previous
//
#include <hip/hip_runtime.h>
#include <hip/hip_bf16.h>

typedef float f4vec  __attribute__((ext_vector_type(4)));
typedef float f16vec __attribute__((ext_vector_type(16)));
typedef short s8vec  __attribute__((ext_vector_type(8)));

#define B_DIM 64
#define N_DIM 64
#define D_DIM 9216
#define SPLIT 8
#define CHUNK 1152          // D_DIM / SPLIT
#define NSTEP (CHUNK / 64)  // 18

// ws layout (bytes):
//   Spart    @ 0        : 64*8*4096*4 = 8388608
//   meanPart @ 8388608  : 64*8*64*4   = 131072
//   Cout     @ 8519680  : 64*64*4     = 16384   (c = inv_L @ mean, fp32)
//   Mb(bf16) @ 8536064  : 64*4096*2   = 524288  (M = inv_L - I, row-major)

__device__ __forceinline__ short f2bf(float f) {
  union { __hip_bfloat16 h; short s; } u;
  u.h = __float2bfloat16(f);
  return u.s;
}

// v_readlane: static VGPR, runtime-uniform (SGPR) lane index is legal.
__device__ __forceinline__ float rdlane(float v, int l) {
  union { float f; int i; } u;
  u.f = v;
  u.i = __builtin_amdgcn_readlane(u.i, l);
  return u.f;
}

// ---------------- Kernel 1: partial Gram + row-sum partials ----------------
__global__ __launch_bounds__(256) void k_cov_partial(
    const float* __restrict__ x, float* __restrict__ Spart,
    float* __restrict__ meanPart) {
  const int s = blockIdx.x, b = blockIdx.y;
  const int t = threadIdx.x;
  const int lane = t & 63, w = t >> 6;
  const int wr = w >> 1, wc = w & 1;
  const int hi = lane >> 5;

  __shared__ float T[64 * 64];

  const float* xb = x + (size_t)b * N_DIM * D_DIM + (size_t)s * CHUNK;
  const int jrow = t >> 2, q = t & 3;
  const float* xrow = xb + (size_t)jrow * D_DIM;

  f16vec acc;
#pragma unroll
  for (int r = 0; r < 16; ++r) acc[r] = 0.0f;
  float msum = 0.0f;

  const int r_a = 32 * wr + (lane & 31);
  const int r_b = 32 * wc + (lane & 31);

  f4vec v[4];
#pragma unroll
  for (int i = 0; i < 4; ++i)
    v[i] = *reinterpret_cast<const f4vec*>(xrow + (i * 4 + q) * 4);

  for (int step = 0; step < NSTEP; ++step) {
    __syncthreads();  // previous step's frag reads done; LDS free
#pragma unroll
    for (int i = 0; i < 4; ++i) {
      const int f = i * 4 + q;
      msum += v[i].x + v[i].y + v[i].z + v[i].w;
      *reinterpret_cast<f4vec*>(&T[jrow * 64 + ((f ^ (jrow & 15)) << 2)]) = v[i];
    }
    __syncthreads();  // tile ready
    if (step + 1 < NSTEP) {
      const float* xn = xrow + (step + 1) * 64;
#pragma unroll
      for (int i = 0; i < 4; ++i)
        v[i] = *reinterpret_cast<const f4vec*>(xn + (i * 4 + q) * 4);
    }
#pragma unroll
    for (int ks = 0; ks < 4; ++ks) {
      const int c0 = ks * 4 + hi * 2;
      f4vec a0 = *reinterpret_cast<const f4vec*>(
          &T[r_a * 64 + ((c0 ^ (r_a & 15)) << 2)]);
      f4vec a1 = *reinterpret_cast<const f4vec*>(
          &T[r_a * 64 + (((c0 + 1) ^ (r_a & 15)) << 2)]);
      f4vec b0 = *reinterpret_cast<const f4vec*>(
          &T[r_b * 64 + ((c0 ^ (r_b & 15)) << 2)]);
      f4vec b1 = *reinterpret_cast<const f4vec*>(
          &T[r_b * 64 + (((c0 + 1) ^ (r_b & 15)) << 2)]);
      s8vec af, bf;
      af[0]=f2bf(a0.x); af[1]=f2bf(a0.y); af[2]=f2bf(a0.z); af[3]=f2bf(a0.w);
      af[4]=f2bf(a1.x); af[5]=f2bf(a1.y); af[6]=f2bf(a1.z); af[7]=f2bf(a1.w);
      bf[0]=f2bf(b0.x); bf[1]=f2bf(b0.y); bf[2]=f2bf(b0.z); bf[3]=f2bf(b0.w);
      bf[4]=f2bf(b1.x); bf[5]=f2bf(b1.y); bf[6]=f2bf(b1.z); bf[7]=f2bf(b1.w);
      acc = __builtin_amdgcn_mfma_f32_32x32x16_bf16(af, bf, acc, 0, 0, 0);
    }
  }

  msum += __shfl_xor(msum, 1);
  msum += __shfl_xor(msum, 2);
  if (q == 0) meanPart[(b * SPLIT + s) * 64 + jrow] = msum;

  float* Sp = Spart + (size_t)(b * SPLIT + s) * 4096;
#pragma unroll
  for (int r = 0; r < 16; ++r) {
    const int i = 32 * wr + (r & 3) + 8 * (r >> 2) + 4 * hi;
    const int j = 32 * wc + (lane & 31);
    Sp[i * 64 + j] = acc[r];
  }
}

// ------ Kernel 2: blocked Cholesky + BLOCKED triangular inverse ------------
// r9/r10 localized k2's remaining ~45-50 us to the 64-serial-iteration
// forward substitution (per-iter: LDS loads -> 16-FMA dot -> 2 dependent
// shfl -> capture, ~500+ cyc exposed). r11 replaces it with the block-2x2
// triangular-inverse identity applied bottom-up (recursive doubling):
//   L0: 8 independent 8x8 diag-block inverses (serial depth 8)
//   L1..L3: correction matmuls Y21 = -Y22*(A21*Y11) at 8/16/32 granularity,
//   fully data-parallel (1-4 elems/thread), f4 A-reads, broadcast/stride-1
//   Y-reads. Serial depth ~8 + 3 levels instead of 64 iterations.
__global__ __launch_bounds__(256) void k_chol_inv(
    const float* __restrict__ Spart, const float* __restrict__ meanPart,
    unsigned short* __restrict__ Mb, float* __restrict__ Cout) {
  const int t = threadIdx.x;
  const int b = blockIdx.x;
  const int wid = t >> 6, lane = t & 63;

  __shared__ float Ash[64 * 68];   // A-bar (lower valid), pitch 68
  __shared__ float Ysh[64 * 68];   // Y = inv(A-bar), lower; upper zeroed
  __shared__ float Tsh[1056];      // level scratch (32x33 max)
  __shared__ float mean_sh[64];
  __shared__ float sqd_sh[64];

  if (t < 64) {
    float mm = 0.0f;
#pragma unroll
    for (int p = 0; p < SPLIT; ++p) mm += meanPart[(b * SPLIT + p) * 64 + t];
    mean_sh[t] = mm * (1.0f / D_DIM);
  }
  __syncthreads();

  // cov reduce: thread t handles f4-chunks f = t + 256*m (coalesced loads).
  {
    const float invD1 = 1.0f / (float)(D_DIM - 1);
    const f4vec* Sp =
        reinterpret_cast<const f4vec*>(Spart + (size_t)(b * SPLIT) * 4096);
#pragma unroll
    for (int m = 0; m < 4; ++m) {
      const int f = t + 256 * m;
      f4vec s = Sp[f];
#pragma unroll
      for (int p = 1; p < SPLIT; ++p) s += Sp[p * 1024 + f];
      const int row = f >> 4, c4 = f & 15;
      const float miD = mean_sh[row] * (float)D_DIM;
      const f4vec mj = *reinterpret_cast<const f4vec*>(&mean_sh[c4 * 4]);
      f4vec r;
      r.x = (s.x - miD * mj.x) * invD1;
      r.y = (s.y - miD * mj.y) * invD1;
      r.z = (s.z - miD * mj.z) * invD1;
      r.w = (s.w - miD * mj.w) * invD1;
      *reinterpret_cast<f4vec*>(&Ash[row * 68 + c4 * 4]) = r;
    }
  }
  __syncthreads();

  // ---- Blocked Cholesky: 8 panels x 8 cols; ONE barrier per panel. ----
#pragma clang loop unroll(disable)
  for (int kb = 0; kb < 8; ++kb) {
    const int K = kb * 8;
    float p[8];
    {
      f4vec pa = *reinterpret_cast<const f4vec*>(&Ash[lane * 68 + K]);
      f4vec pb = *reinterpret_cast<const f4vec*>(&Ash[lane * 68 + K + 4]);
      p[0]=pa.x; p[1]=pa.y; p[2]=pa.z; p[3]=pa.w;
      p[4]=pb.x; p[5]=pb.y; p[6]=pb.z; p[7]=pb.w;
    }
    float fl[8];
#pragma unroll
    for (int c = 0; c < 8; ++c) {
      const int kc = K + c;
      const float d = rdlane(p[c], kc);
      const float inv = __builtin_amdgcn_rcpf(d);
      const float f = (lane > kc) ? p[c] * inv : 0.0f;
      fl[c] = f;
#pragma unroll
      for (int j = c + 1; j < 8; ++j)
        p[j] -= f * rdlane(p[j], kc);
    }
    if (wid == (kb >> 1)) {
      f4vec pa, pb;
      pa.x=p[0]; pa.y=p[1]; pa.z=p[2]; pa.w=p[3];
      pb.x=p[4]; pb.y=p[5]; pb.z=p[6]; pb.w=p[7];
      *reinterpret_cast<f4vec*>(&Ash[lane * 68 + K]) = pa;
      *reinterpret_cast<f4vec*>(&Ash[lane * 68 + K + 4]) = pb;
    }
#pragma unroll
    for (int q = 0; q < 4; ++q) {
      const int j0 = 16 * wid + 4 * q;
      if (j0 >= K + 8) {                      // wave-uniform branch
        f4vec o = *reinterpret_cast<const f4vec*>(&Ash[lane * 68 + j0]);
        float sx = 0.0f, sy = 0.0f, sz = 0.0f, sw = 0.0f;
#pragma unroll
        for (int c = 0; c < 8; ++c) {
          sx += fl[c] * rdlane(p[c], j0 + 0);
          sy += fl[c] * rdlane(p[c], j0 + 1);
          sz += fl[c] * rdlane(p[c], j0 + 2);
          sw += fl[c] * rdlane(p[c], j0 + 3);
        }
        o.x -= sx; o.y -= sy; o.z -= sz; o.w -= sw;
        *reinterpret_cast<f4vec*>(&Ash[lane * 68 + j0]) = o;
      }
    }
    __syncthreads();
  }

  // ---- Zero Y (upper blocks must read as exact 0) + sqrt(diag). ----
  {
    f4vec z; z.x = z.y = z.z = z.w = 0.0f;
    for (int e = t; e < 64 * 17; e += 256)
      *reinterpret_cast<f4vec*>(&Ysh[e * 4]) = z;
    if (t < 64) sqd_sh[t] = __builtin_amdgcn_sqrtf(Ash[t * 68 + t]);
  }
  __syncthreads();

  // ---- L0: invert 8 diagonal 8x8 blocks (thread = (block q, column cL)) --
  if (t < 64) {
    const int q = t >> 3, cL = t & 7, base = q * 8;
    float yv[8];
#pragma unroll
    for (int i = 0; i < 8; ++i) yv[i] = 0.0f;
#pragma unroll
    for (int i = 0; i < 8; ++i) {
      float s = 0.0f;
#pragma unroll
      for (int j = 0; j < 8; ++j)
        if (j < i) s += Ash[(base + i) * 68 + base + j] * yv[j];
      const float del = (i == cL) ? 1.0f : 0.0f;
      float yi = (del - s) * __builtin_amdgcn_rcpf(Ash[(base + i) * 68 + base + i]);
      yi = (i >= cL) ? yi : 0.0f;   // strictly-upper of block = 0
      yv[i] = yi;
      Ysh[(base + i) * 68 + base + cL] = yi;
    }
  }
  __syncthreads();

  // ---- L1: 4 pairs at 16-granularity; wave p owns pair p. ----
  {
    const int p = wid, e = t & 63, r = e >> 3, cc = e & 7;
    const int R = p * 16 + 8 + r, J = p * 16;
    // step A: T = A21 * Y11  (8x8x8)
    float s = 0.0f;
    {
      f4vec a0 = *reinterpret_cast<const f4vec*>(&Ash[R * 68 + J]);
      f4vec a1 = *reinterpret_cast<const f4vec*>(&Ash[R * 68 + J + 4]);
      s += a0.x * Ysh[(J + 0) * 68 + J + cc] + a0.y * Ysh[(J + 1) * 68 + J + cc]
         + a0.z * Ysh[(J + 2) * 68 + J + cc] + a0.w * Ysh[(J + 3) * 68 + J + cc];
      s += a1.x * Ysh[(J + 4) * 68 + J + cc] + a1.y * Ysh[(J + 5) * 68 + J + cc]
         + a1.z * Ysh[(J + 6) * 68 + J + cc] + a1.w * Ysh[(J + 7) * 68 + J + cc];
    }
    Tsh[p * 264 + r * 33 + cc] = s;
    __syncthreads();
    // step B: Y21 = -Y22 * T
    float s2 = 0.0f;
    {
      f4vec y0 = *reinterpret_cast<const f4vec*>(&Ysh[R * 68 + J + 8]);
      f4vec y1 = *reinterpret_cast<const f4vec*>(&Ysh[R * 68 + J + 12]);
      const float* Tc = &Tsh[p * 264 + cc];
      s2 += y0.x * Tc[0 * 33] + y0.y * Tc[1 * 33]
          + y0.z * Tc[2 * 33] + y0.w * Tc[3 * 33];
      s2 += y1.x * Tc[4 * 33] + y1.y * Tc[5 * 33]
          + y1.z * Tc[6 * 33] + y1.w * Tc[7 * 33];
    }
    __syncthreads();               // Tsh reuse at L2
    Ysh[R * 68 + J + cc] = -s2;
  }
  __syncthreads();

  // ---- L2: 2 pairs at 32-granularity; waves {0,1}->pair0, {2,3}->pair1. --
  {
    const int p = t >> 7, tid = t & 127;
    // step A: T = A21 * Y11  (16x16x16), 2 elems/thread
    float sa[2];
#pragma unroll
    for (int m = 0; m < 2; ++m) {
      const int E = tid + 128 * m, r = E >> 4, cc = E & 15;
      const int R = p * 32 + 16 + r, J = p * 32;
      float s = 0.0f;
#pragma unroll
      for (int k4 = 0; k4 < 4; ++k4) {
        f4vec a = *reinterpret_cast<const f4vec*>(&Ash[R * 68 + J + k4 * 4]);
        const int k = k4 * 4;
        s += a.x * Ysh[(J + k + 0) * 68 + J + cc]
           + a.y * Ysh[(J + k + 1) * 68 + J + cc]
           + a.z * Ysh[(J + k + 2) * 68 + J + cc]
           + a.w * Ysh[(J + k + 3) * 68 + J + cc];
      }
      sa[m] = s;
    }
#pragma unroll
    for (int m = 0; m < 2; ++m) {
      const int E = tid + 128 * m, r = E >> 4, cc = E & 15;
      Tsh[p * 528 + r * 33 + cc] = sa[m];
    }
    __syncthreads();
    // step B: Y21 = -Y22 * T
    float sb[2];
#pragma unroll
    for (int m = 0; m < 2; ++m) {
      const int E = tid + 128 * m, r = E >> 4, cc = E & 15;
      const int R = p * 32 + 16 + r, J = p * 32;
      float s = 0.0f;
      const float* Tc = &Tsh[p * 528 + cc];
#pragma unroll
      for (int k4 = 0; k4 < 4; ++k4) {
        f4vec y = *reinterpret_cast<const f4vec*>(&Ysh[R * 68 + J + 16 + k4 * 4]);
        const int k = k4 * 4;
        s += y.x * Tc[(k + 0) * 33] + y.y * Tc[(k + 1) * 33]
           + y.z * Tc[(k + 2) * 33] + y.w * Tc[(k + 3) * 33];
      }
      sb[m] = s;
    }
    __syncthreads();               // Tsh reuse at L3
#pragma unroll
    for (int m = 0; m < 2; ++m) {
      const int E = tid + 128 * m, r = E >> 4, cc = E & 15;
      const int R = p * 32 + 16 + r, J = p * 32;
      Ysh[R * 68 + J + cc] = -sb[m];
    }
  }
  __syncthreads();

  // ---- L3: final pair (rows 32..63, cols 0..31), 4 elems/thread. ----
  {
    // step A: T = A21 * Y11  (32x32x32)
    float sa[4];
#pragma unroll
    for (int m = 0; m < 4; ++m) {
      const int E = t + 256 * m, r = E >> 5, cc = E & 31;
      const int R = 32 + r;
      float s = 0.0f;
#pragma unroll
      for (int k4 = 0; k4 < 8; ++k4) {
        f4vec a = *reinterpret_cast<const f4vec*>(&Ash[R * 68 + k4 * 4]);
        const int k = k4 * 4;
        s += a.x * Ysh[(k + 0) * 68 + cc] + a.y * Ysh[(k + 1) * 68 + cc]
           + a.z * Ysh[(k + 2) * 68 + cc] + a.w * Ysh[(k + 3) * 68 + cc];
      }
      sa[m] = s;
    }
#pragma unroll
    for (int m = 0; m < 4; ++m) {
      const int E = t + 256 * m, r = E >> 5, cc = E & 31;
      Tsh[r * 33 + cc] = sa[m];
    }
    __syncthreads();
    // step B: Y21 = -Y22 * T
    float sb[4];
#pragma unroll
    for (int m = 0; m < 4; ++m) {
      const int E = t + 256 * m, r = E >> 5, cc = E & 31;
      const int R = 32 + r;
      float s = 0.0f;
      const float* Tc = &Tsh[cc];
#pragma unroll
      for (int k4 = 0; k4 < 8; ++k4) {
        f4vec y = *reinterpret_cast<const f4vec*>(&Ysh[R * 68 + 32 + k4 * 4]);
        const int k = k4 * 4;
        s += y.x * Tc[(k + 0) * 33] + y.y * Tc[(k + 1) * 33]
           + y.z * Tc[(k + 2) * 33] + y.w * Tc[(k + 3) * 33];
      }
      sb[m] = s;
    }
#pragma unroll
    for (int m = 0; m < 4; ++m) {
      const int E = t + 256 * m, r = E >> 5, cc = E & 31;
      Ysh[(32 + r) * 68 + cc] = -sb[m];
    }
  }
  __syncthreads();

  // ---- Epilogue: Mb = bf16(inv_L - I), Cvec = inv_L @ mean. ----
  const size_t mb_base = (size_t)b * 4096;
#pragma unroll
  for (int m = 0; m < 16; ++m) {
    const int e = t + 256 * m, i = e >> 6, j = e & 63;
    float v = 0.0f;
    if (j <= i) {
      v = sqd_sh[i] * Ysh[i * 68 + j];
      if (j == i) v -= 1.0f;
    }
    Mb[mb_base + e] = (unsigned short)f2bf(v);
  }
  {
    const int i2 = t >> 2, g = t & 3;
    float pz = 0.0f;
#pragma unroll
    for (int s2 = 0; s2 < 16; ++s2) {
      const int cc = g + 4 * s2;
      pz += Ysh[i2 * 68 + cc] * mean_sh[cc];
    }
    pz += __shfl_xor(pz, 1);
    pz += __shfl_xor(pz, 2);
    if (g == 0) Cout[b * 64 + i2] = pz * sqd_sh[i2];
  }
}

// ---------------- Kernel 3: out = x + M@x - c*1^T  (LDS-free) --------------
__global__ __launch_bounds__(256) void k_whiten(
    const float* __restrict__ x, const float* __restrict__ Cvec,
    const unsigned short* __restrict__ Mb, float* __restrict__ out) {
  const int b = blockIdx.y;
  const int t = threadIdx.x;
  const int wid = t >> 6, lane = t & 63;
  const int lo = lane & 31, hi = lane >> 5;

  s8vec mfrag[2][4];
  const unsigned short* Mbb = Mb + (size_t)b * 4096;
#pragma unroll
  for (int wr = 0; wr < 2; ++wr)
#pragma unroll
    for (int ks = 0; ks < 4; ++ks)
      mfrag[wr][ks] = *reinterpret_cast<const s8vec*>(
          Mbb + (32 * wr + lo) * 64 + ks * 16 + hi * 8);

  float cv[2][16];
  const float* cb = Cvec + b * 64;
#pragma unroll
  for (int wr = 0; wr < 2; ++wr)
#pragma unroll
    for (int r = 0; r < 16; ++r)
      cv[wr][r] = cb[32 * wr + (r & 3) + 8 * (r >> 2) + 4 * hi];

  const float* xb = x + (size_t)b * N_DIM * D_DIM;
  float* ob = out + (size_t)b * N_DIM * D_DIM;

#pragma unroll
  for (int n = 0; n < 2; ++n) {
    const int d0 = blockIdx.x * 256 + wid * 64 + n * 32;
    f16vec acc0, acc1;
#pragma unroll
    for (int r = 0; r < 16; ++r) { acc0[r] = 0.0f; acc1[r] = 0.0f; }

#pragma unroll
    for (int ks = 0; ks < 4; ++ks) {
      const float* colp = xb + (size_t)(16 * ks + 8 * hi) * D_DIM + d0 + lo;
      s8vec bf;
#pragma unroll
      for (int e = 0; e < 8; ++e) bf[e] = f2bf(colp[(size_t)e * D_DIM]);
      acc0 = __builtin_amdgcn_mfma_f32_32x32x16_bf16(mfrag[0][ks], bf, acc0, 0, 0, 0);
      acc1 = __builtin_amdgcn_mfma_f32_32x32x16_bf16(mfrag[1][ks], bf, acc1, 0, 0, 0);
    }

#pragma unroll
    for (int r = 0; r < 16; ++r) {
      const int row = (r & 3) + 8 * (r >> 2) + 4 * hi;
      const size_t off0 = (size_t)row * D_DIM + d0 + lo;
      ob[off0] = acc0[r] + xb[off0] - cv[0][r];
      const size_t off1 = (size_t)(row + 32) * D_DIM + d0 + lo;
      ob[off1] = acc1[r] + xb[off1] - cv[1][r];
    }
  }
}

extern "C" void kernel_launch(void* const* d_in, const int* in_sizes, int n_in,
                              void* d_out, int out_size, void* d_ws,
                              size_t ws_size, hipStream_t stream) {
  const float* x = (const float*)d_in[0];
  float* out = (float*)d_out;
  char* ws = (char*)d_ws;

  float* Spart = (float*)ws;                            // 8 MB
  float* meanPart = (float*)(ws + 8388608);             // 128 KB
  float* Cout = (float*)(ws + 8519680);                 // 16 KB
  unsigned short* Mb = (unsigned short*)(ws + 8536064); // 512 KB

  k_cov_partial<<<dim3(SPLIT, B_DIM), 256, 0, stream>>>(x, Spart, meanPart);
  k_chol_inv<<<dim3(B_DIM), 256, 0, stream>>>(Spart, meanPart, Mb, Cout);
  k_whiten<<<dim3(D_DIM / 256, B_DIM), 256, 0, stream>>>(x, Cout, Mb, out);
}

// Round 12
// 100.189 us; speedup vs baseline: 1.7581x; 1.0139x over previous
//
#include <hip/hip_runtime.h>
#include <hip/hip_bf16.h>

typedef float f4vec  __attribute__((ext_vector_type(4)));
typedef float f16vec __attribute__((ext_vector_type(16)));
typedef short s8vec  __attribute__((ext_vector_type(8)));

#define B_DIM 64
#define N_DIM 64
#define D_DIM 9216
#define SPLIT 8
#define CHUNK 1152          // D_DIM / SPLIT
#define NSTEP (CHUNK / 64)  // 18

// ws layout (bytes):
//   Spart    @ 0        : 64*8*4096*4 = 8388608
//   meanPart @ 8388608  : 64*8*64*4   = 131072
//   Cout     @ 8519680  : 64*64*4     = 16384   (c = inv_L @ mean, fp32)
//   Mb(bf16) @ 8536064  : 64*4096*2   = 524288  (M = inv_L - I, row-major)

__device__ __forceinline__ short f2bf(float f) {
  union { __hip_bfloat16 h; short s; } u;
  u.h = __float2bfloat16(f);
  return u.s;
}

// v_readlane: static VGPR, manifestly-uniform (loop-scalar) lane index ONLY.
__device__ __forceinline__ float rdlane(float v, int l) {
  union { float f; int i; } u;
  u.f = v;
  u.i = __builtin_amdgcn_readlane(u.i, l);
  return u.f;
}

// ---------------- Kernel 1: partial Gram + row-sum partials ----------------
__global__ __launch_bounds__(256) void k_cov_partial(
    const float* __restrict__ x, float* __restrict__ Spart,
    float* __restrict__ meanPart) {
  const int s = blockIdx.x, b = blockIdx.y;
  const int t = threadIdx.x;
  const int lane = t & 63, w = t >> 6;
  const int wr = w >> 1, wc = w & 1;
  const int hi = lane >> 5;

  __shared__ float T[64 * 64];

  const float* xb = x + (size_t)b * N_DIM * D_DIM + (size_t)s * CHUNK;
  const int jrow = t >> 2, q = t & 3;
  const float* xrow = xb + (size_t)jrow * D_DIM;

  f16vec acc;
#pragma unroll
  for (int r = 0; r < 16; ++r) acc[r] = 0.0f;
  float msum = 0.0f;

  const int r_a = 32 * wr + (lane & 31);
  const int r_b = 32 * wc + (lane & 31);

  f4vec v[4];
#pragma unroll
  for (int i = 0; i < 4; ++i)
    v[i] = *reinterpret_cast<const f4vec*>(xrow + (i * 4 + q) * 4);

  for (int step = 0; step < NSTEP; ++step) {
    __syncthreads();  // previous step's frag reads done; LDS free
#pragma unroll
    for (int i = 0; i < 4; ++i) {
      const int f = i * 4 + q;
      msum += v[i].x + v[i].y + v[i].z + v[i].w;
      *reinterpret_cast<f4vec*>(&T[jrow * 64 + ((f ^ (jrow & 15)) << 2)]) = v[i];
    }
    __syncthreads();  // tile ready
    if (step + 1 < NSTEP) {
      const float* xn = xrow + (step + 1) * 64;
#pragma unroll
      for (int i = 0; i < 4; ++i)
        v[i] = *reinterpret_cast<const f4vec*>(xn + (i * 4 + q) * 4);
    }
#pragma unroll
    for (int ks = 0; ks < 4; ++ks) {
      const int c0 = ks * 4 + hi * 2;
      f4vec a0 = *reinterpret_cast<const f4vec*>(
          &T[r_a * 64 + ((c0 ^ (r_a & 15)) << 2)]);
      f4vec a1 = *reinterpret_cast<const f4vec*>(
          &T[r_a * 64 + (((c0 + 1) ^ (r_a & 15)) << 2)]);
      f4vec b0 = *reinterpret_cast<const f4vec*>(
          &T[r_b * 64 + ((c0 ^ (r_b & 15)) << 2)]);
      f4vec b1 = *reinterpret_cast<const f4vec*>(
          &T[r_b * 64 + (((c0 + 1) ^ (r_b & 15)) << 2)]);
      s8vec af, bf;
      af[0]=f2bf(a0.x); af[1]=f2bf(a0.y); af[2]=f2bf(a0.z); af[3]=f2bf(a0.w);
      af[4]=f2bf(a1.x); af[5]=f2bf(a1.y); af[6]=f2bf(a1.z); af[7]=f2bf(a1.w);
      bf[0]=f2bf(b0.x); bf[1]=f2bf(b0.y); bf[2]=f2bf(b0.z); bf[3]=f2bf(b0.w);
      bf[4]=f2bf(b1.x); bf[5]=f2bf(b1.y); bf[6]=f2bf(b1.z); bf[7]=f2bf(b1.w);
      acc = __builtin_amdgcn_mfma_f32_32x32x16_bf16(af, bf, acc, 0, 0, 0);
    }
  }

  msum += __shfl_xor(msum, 1);
  msum += __shfl_xor(msum, 2);
  if (q == 0) meanPart[(b * SPLIT + s) * 64 + jrow] = msum;

  float* Sp = Spart + (size_t)(b * SPLIT + s) * 4096;
#pragma unroll
  for (int r = 0; r < 16; ++r) {
    const int i = 32 * wr + (r & 3) + 8 * (r >> 2) + 4 * hi;
    const int j = 32 * wc + (lane & 31);
    Sp[i * 64 + j] = acc[r];
  }
}

// ------ Kernel 2: blocked Cholesky + BLOCKED triangular inverse ------------
// r12 change (isolated): the chol trailing update used
// rdlane(p[c], 16*wid+4*q+e) -- a threadIdx-derived lane index the compiler
// cannot prove uniform, so each readlane legalizes to a conservative
// waterfall/readfirstlane sequence (128 per panel per wave, ~20-40K cyc
// total: the unexplained ~30 us of chol). Now: each wave stages its
// finalized pivot column p[c] into a PRIVATE LDS strip Prow[wid] (one
// ds_write per column, wave-synchronous), and the trailing update reads
// Prow[wid][c][j0..j0+3] as f4 same-address broadcast LDS reads -- 8
// independent pipelined reads per quad, waterfall-free. Bit-identical math.
__global__ __launch_bounds__(256) void k_chol_inv(
    const float* __restrict__ Spart, const float* __restrict__ meanPart,
    unsigned short* __restrict__ Mb, float* __restrict__ Cout) {
  const int t = threadIdx.x;
  const int b = blockIdx.x;
  const int wid = t >> 6, lane = t & 63;

  __shared__ float Ash[64 * 68];   // A-bar (lower valid), pitch 68
  __shared__ float Ysh[64 * 68];   // Y = inv(A-bar), lower; upper zeroed
  __shared__ float Prow[4][8 * 64];// per-wave staged pivot columns (8 KB)
  __shared__ float Tsh[1056];      // level scratch (32x33 max)
  __shared__ float mean_sh[64];
  __shared__ float sqd_sh[64];

  if (t < 64) {
    float mm = 0.0f;
#pragma unroll
    for (int p = 0; p < SPLIT; ++p) mm += meanPart[(b * SPLIT + p) * 64 + t];
    mean_sh[t] = mm * (1.0f / D_DIM);
  }
  __syncthreads();

  // cov reduce: thread t handles f4-chunks f = t + 256*m (coalesced loads).
  {
    const float invD1 = 1.0f / (float)(D_DIM - 1);
    const f4vec* Sp =
        reinterpret_cast<const f4vec*>(Spart + (size_t)(b * SPLIT) * 4096);
#pragma unroll
    for (int m = 0; m < 4; ++m) {
      const int f = t + 256 * m;
      f4vec s = Sp[f];
#pragma unroll
      for (int p = 1; p < SPLIT; ++p) s += Sp[p * 1024 + f];
      const int row = f >> 4, c4 = f & 15;
      const float miD = mean_sh[row] * (float)D_DIM;
      const f4vec mj = *reinterpret_cast<const f4vec*>(&mean_sh[c4 * 4]);
      f4vec r;
      r.x = (s.x - miD * mj.x) * invD1;
      r.y = (s.y - miD * mj.y) * invD1;
      r.z = (s.z - miD * mj.z) * invD1;
      r.w = (s.w - miD * mj.w) * invD1;
      *reinterpret_cast<f4vec*>(&Ash[row * 68 + c4 * 4]) = r;
    }
  }
  __syncthreads();

  // ---- Blocked Cholesky: 8 panels x 8 cols; ONE barrier per panel. ----
#pragma clang loop unroll(disable)
  for (int kb = 0; kb < 8; ++kb) {
    const int K = kb * 8;
    float p[8];
    {
      f4vec pa = *reinterpret_cast<const f4vec*>(&Ash[lane * 68 + K]);
      f4vec pb = *reinterpret_cast<const f4vec*>(&Ash[lane * 68 + K + 4]);
      p[0]=pa.x; p[1]=pa.y; p[2]=pa.z; p[3]=pa.w;
      p[4]=pb.x; p[5]=pb.y; p[6]=pb.z; p[7]=pb.w;
    }
    float fl[8];
#pragma unroll
    for (int c = 0; c < 8; ++c) {
      const int kc = K + c;                 // loop-scalar: uniform readlane
      Prow[wid][c * 64 + lane] = p[c];      // stage finalized column c
      const float d = rdlane(p[c], kc);
      const float inv = __builtin_amdgcn_rcpf(d);
      const float f = (lane > kc) ? p[c] * inv : 0.0f;
      fl[c] = f;
#pragma unroll
      for (int j = c + 1; j < 8; ++j)
        p[j] -= f * rdlane(p[j], kc);
    }
    if (wid == (kb >> 1)) {
      f4vec pa, pb;
      pa.x=p[0]; pa.y=p[1]; pa.z=p[2]; pa.w=p[3];
      pb.x=p[4]; pb.y=p[5]; pb.z=p[6]; pb.w=p[7];
      *reinterpret_cast<f4vec*>(&Ash[lane * 68 + K]) = pa;
      *reinterpret_cast<f4vec*>(&Ash[lane * 68 + K + 4]) = pb;
    }
    // Trailing rank-8 update: wave owns 16 cols (4 f4-quads). Broadcast row
    // values come from Prow[wid] (f4 same-address reads, wave-synchronous
    // visibility; compiler inserts the lgkmcnt wait). Note Prow[c][j] holds
    // the PRE-pivot-c value of column c at row j, which for j > K+7 (the
    // only j used here) equals the finalized A-bar[K+c][j] by symmetry.
#pragma unroll
    for (int q = 0; q < 4; ++q) {
      const int j0 = 16 * wid + 4 * q;
      if (j0 >= K + 8) {                      // wave-uniform branch
        f4vec o = *reinterpret_cast<const f4vec*>(&Ash[lane * 68 + j0]);
        float sx = 0.0f, sy = 0.0f, sz = 0.0f, sw = 0.0f;
#pragma unroll
        for (int c = 0; c < 8; ++c) {
          const f4vec rk =
              *reinterpret_cast<const f4vec*>(&Prow[wid][c * 64 + j0]);
          sx += fl[c] * rk.x;
          sy += fl[c] * rk.y;
          sz += fl[c] * rk.z;
          sw += fl[c] * rk.w;
        }
        o.x -= sx; o.y -= sy; o.z -= sz; o.w -= sw;
        *reinterpret_cast<f4vec*>(&Ash[lane * 68 + j0]) = o;
      }
    }
    __syncthreads();
  }

  // ---- Zero Y (upper blocks must read as exact 0) + sqrt(diag). ----
  {
    f4vec z; z.x = z.y = z.z = z.w = 0.0f;
    for (int e = t; e < 64 * 17; e += 256)
      *reinterpret_cast<f4vec*>(&Ysh[e * 4]) = z;
    if (t < 64) sqd_sh[t] = __builtin_amdgcn_sqrtf(Ash[t * 68 + t]);
  }
  __syncthreads();

  // ---- L0: invert 8 diagonal 8x8 blocks (thread = (block q, column cL)) --
  if (t < 64) {
    const int q = t >> 3, cL = t & 7, base = q * 8;
    float yv[8];
#pragma unroll
    for (int i = 0; i < 8; ++i) yv[i] = 0.0f;
#pragma unroll
    for (int i = 0; i < 8; ++i) {
      float s = 0.0f;
#pragma unroll
      for (int j = 0; j < 8; ++j)
        if (j < i) s += Ash[(base + i) * 68 + base + j] * yv[j];
      const float del = (i == cL) ? 1.0f : 0.0f;
      float yi = (del - s) * __builtin_amdgcn_rcpf(Ash[(base + i) * 68 + base + i]);
      yi = (i >= cL) ? yi : 0.0f;   // strictly-upper of block = 0
      yv[i] = yi;
      Ysh[(base + i) * 68 + base + cL] = yi;
    }
  }
  __syncthreads();

  // ---- L1: 4 pairs at 16-granularity; wave p owns pair p. ----
  {
    const int p = wid, e = t & 63, r = e >> 3, cc = e & 7;
    const int R = p * 16 + 8 + r, J = p * 16;
    // step A: T = A21 * Y11  (8x8x8)
    float s = 0.0f;
    {
      f4vec a0 = *reinterpret_cast<const f4vec*>(&Ash[R * 68 + J]);
      f4vec a1 = *reinterpret_cast<const f4vec*>(&Ash[R * 68 + J + 4]);
      s += a0.x * Ysh[(J + 0) * 68 + J + cc] + a0.y * Ysh[(J + 1) * 68 + J + cc]
         + a0.z * Ysh[(J + 2) * 68 + J + cc] + a0.w * Ysh[(J + 3) * 68 + J + cc];
      s += a1.x * Ysh[(J + 4) * 68 + J + cc] + a1.y * Ysh[(J + 5) * 68 + J + cc]
         + a1.z * Ysh[(J + 6) * 68 + J + cc] + a1.w * Ysh[(J + 7) * 68 + J + cc];
    }
    Tsh[p * 264 + r * 33 + cc] = s;
    __syncthreads();
    // step B: Y21 = -Y22 * T
    float s2 = 0.0f;
    {
      f4vec y0 = *reinterpret_cast<const f4vec*>(&Ysh[R * 68 + J + 8]);
      f4vec y1 = *reinterpret_cast<const f4vec*>(&Ysh[R * 68 + J + 12]);
      const float* Tc = &Tsh[p * 264 + cc];
      s2 += y0.x * Tc[0 * 33] + y0.y * Tc[1 * 33]
          + y0.z * Tc[2 * 33] + y0.w * Tc[3 * 33];
      s2 += y1.x * Tc[4 * 33] + y1.y * Tc[5 * 33]
          + y1.z * Tc[6 * 33] + y1.w * Tc[7 * 33];
    }
    __syncthreads();               // Tsh reuse at L2
    Ysh[R * 68 + J + cc] = -s2;
  }
  __syncthreads();

  // ---- L2: 2 pairs at 32-granularity; waves {0,1}->pair0, {2,3}->pair1. --
  {
    const int p = t >> 7, tid = t & 127;
    // step A: T = A21 * Y11  (16x16x16), 2 elems/thread
    float sa[2];
#pragma unroll
    for (int m = 0; m < 2; ++m) {
      const int E = tid + 128 * m, r = E >> 4, cc = E & 15;
      const int R = p * 32 + 16 + r, J = p * 32;
      float s = 0.0f;
#pragma unroll
      for (int k4 = 0; k4 < 4; ++k4) {
        f4vec a = *reinterpret_cast<const f4vec*>(&Ash[R * 68 + J + k4 * 4]);
        const int k = k4 * 4;
        s += a.x * Ysh[(J + k + 0) * 68 + J + cc]
           + a.y * Ysh[(J + k + 1) * 68 + J + cc]
           + a.z * Ysh[(J + k + 2) * 68 + J + cc]
           + a.w * Ysh[(J + k + 3) * 68 + J + cc];
      }
      sa[m] = s;
    }
#pragma unroll
    for (int m = 0; m < 2; ++m) {
      const int E = tid + 128 * m, r = E >> 4, cc = E & 15;
      Tsh[p * 528 + r * 33 + cc] = sa[m];
    }
    __syncthreads();
    // step B: Y21 = -Y22 * T
    float sb[2];
#pragma unroll
    for (int m = 0; m < 2; ++m) {
      const int E = tid + 128 * m, r = E >> 4, cc = E & 15;
      const int R = p * 32 + 16 + r, J = p * 32;
      float s = 0.0f;
      const float* Tc = &Tsh[p * 528 + cc];
#pragma unroll
      for (int k4 = 0; k4 < 4; ++k4) {
        f4vec y = *reinterpret_cast<const f4vec*>(&Ysh[R * 68 + J + 16 + k4 * 4]);
        const int k = k4 * 4;
        s += y.x * Tc[(k + 0) * 33] + y.y * Tc[(k + 1) * 33]
           + y.z * Tc[(k + 2) * 33] + y.w * Tc[(k + 3) * 33];
      }
      sb[m] = s;
    }
    __syncthreads();               // Tsh reuse at L3
#pragma unroll
    for (int m = 0; m < 2; ++m) {
      const int E = tid + 128 * m, r = E >> 4, cc = E & 15;
      const int R = p * 32 + 16 + r, J = p * 32;
      Ysh[R * 68 + J + cc] = -sb[m];
    }
  }
  __syncthreads();

  // ---- L3: final pair (rows 32..63, cols 0..31), 4 elems/thread. ----
  {
    // step A: T = A21 * Y11  (32x32x32)
    float sa[4];
#pragma unroll
    for (int m = 0; m < 4; ++m) {
      const int E = t + 256 * m, r = E >> 5, cc = E & 31;
      const int R = 32 + r;
      float s = 0.0f;
#pragma unroll
      for (int k4 = 0; k4 < 8; ++k4) {
        f4vec a = *reinterpret_cast<const f4vec*>(&Ash[R * 68 + k4 * 4]);
        const int k = k4 * 4;
        s += a.x * Ysh[(k + 0) * 68 + cc] + a.y * Ysh[(k + 1) * 68 + cc]
           + a.z * Ysh[(k + 2) * 68 + cc] + a.w * Ysh[(k + 3) * 68 + cc];
      }
      sa[m] = s;
    }
#pragma unroll
    for (int m = 0; m < 4; ++m) {
      const int E = t + 256 * m, r = E >> 5, cc = E & 31;
      Tsh[r * 33 + cc] = sa[m];
    }
    __syncthreads();
    // step B: Y21 = -Y22 * T
    float sb[4];
#pragma unroll
    for (int m = 0; m < 4; ++m) {
      const int E = t + 256 * m, r = E >> 5, cc = E & 31;
      const int R = 32 + r;
      float s = 0.0f;
      const float* Tc = &Tsh[cc];
#pragma unroll
      for (int k4 = 0; k4 < 8; ++k4) {
        f4vec y = *reinterpret_cast<const f4vec*>(&Ysh[R * 68 + 32 + k4 * 4]);
        const int k = k4 * 4;
        s += y.x * Tc[(k + 0) * 33] + y.y * Tc[(k + 1) * 33]
           + y.z * Tc[(k + 2) * 33] + y.w * Tc[(k + 3) * 33];
      }
      sb[m] = s;
    }
#pragma unroll
    for (int m = 0; m < 4; ++m) {
      const int E = t + 256 * m, r = E >> 5, cc = E & 31;
      Ysh[(32 + r) * 68 + cc] = -sb[m];
    }
  }
  __syncthreads();

  // ---- Epilogue: Mb = bf16(inv_L - I), Cvec = inv_L @ mean. ----
  const size_t mb_base = (size_t)b * 4096;
#pragma unroll
  for (int m = 0; m < 16; ++m) {
    const int e = t + 256 * m, i = e >> 6, j = e & 63;
    float v = 0.0f;
    if (j <= i) {
      v = sqd_sh[i] * Ysh[i * 68 + j];
      if (j == i) v -= 1.0f;
    }
    Mb[mb_base + e] = (unsigned short)f2bf(v);
  }
  {
    const int i2 = t >> 2, g = t & 3;
    float pz = 0.0f;
#pragma unroll
    for (int s2 = 0; s2 < 16; ++s2) {
      const int cc = g + 4 * s2;
      pz += Ysh[i2 * 68 + cc] * mean_sh[cc];
    }
    pz += __shfl_xor(pz, 1);
    pz += __shfl_xor(pz, 2);
    if (g == 0) Cout[b * 64 + i2] = pz * sqd_sh[i2];
  }
}

// ---------------- Kernel 3: out = x + M@x - c*1^T  (LDS-free) --------------
__global__ __launch_bounds__(256) void k_whiten(
    const float* __restrict__ x, const float* __restrict__ Cvec,
    const unsigned short* __restrict__ Mb, float* __restrict__ out) {
  const int b = blockIdx.y;
  const int t = threadIdx.x;
  const int wid = t >> 6, lane = t & 63;
  const int lo = lane & 31, hi = lane >> 5;

  s8vec mfrag[2][4];
  const unsigned short* Mbb = Mb + (size_t)b * 4096;
#pragma unroll
  for (int wr = 0; wr < 2; ++wr)
#pragma unroll
    for (int ks = 0; ks < 4; ++ks)
      mfrag[wr][ks] = *reinterpret_cast<const s8vec*>(
          Mbb + (32 * wr + lo) * 64 + ks * 16 + hi * 8);

  float cv[2][16];
  const float* cb = Cvec + b * 64;
#pragma unroll
  for (int wr = 0; wr < 2; ++wr)
#pragma unroll
    for (int r = 0; r < 16; ++r)
      cv[wr][r] = cb[32 * wr + (r & 3) + 8 * (r >> 2) + 4 * hi];

  const float* xb = x + (size_t)b * N_DIM * D_DIM;
  float* ob = out + (size_t)b * N_DIM * D_DIM;

#pragma unroll
  for (int n = 0; n < 2; ++n) {
    const int d0 = blockIdx.x * 256 + wid * 64 + n * 32;
    f16vec acc0, acc1;
#pragma unroll
    for (int r = 0; r < 16; ++r) { acc0[r] = 0.0f; acc1[r] = 0.0f; }

#pragma unroll
    for (int ks = 0; ks < 4; ++ks) {
      const float* colp = xb + (size_t)(16 * ks + 8 * hi) * D_DIM + d0 + lo;
      s8vec bf;
#pragma unroll
      for (int e = 0; e < 8; ++e) bf[e] = f2bf(colp[(size_t)e * D_DIM]);
      acc0 = __builtin_amdgcn_mfma_f32_32x32x16_bf16(mfrag[0][ks], bf, acc0, 0, 0, 0);
      acc1 = __builtin_amdgcn_mfma_f32_32x32x16_bf16(mfrag[1][ks], bf, acc1, 0, 0, 0);
    }

#pragma unroll
    for (int r = 0; r < 16; ++r) {
      const int row = (r & 3) + 8 * (r >> 2) + 4 * hi;
      const size_t off0 = (size_t)row * D_DIM + d0 + lo;
      ob[off0] = acc0[r] + xb[off0] - cv[0][r];
      const size_t off1 = (size_t)(row + 32) * D_DIM + d0 + lo;
      ob[off1] = acc1[r] + xb[off1] - cv[1][r];
    }
  }
}

extern "C" void kernel_launch(void* const* d_in, const int* in_sizes, int n_in,
                              void* d_out, int out_size, void* d_ws,
                              size_t ws_size, hipStream_t stream) {
  const float* x = (const float*)d_in[0];
  float* out = (float*)d_out;
  char* ws = (char*)d_ws;

  float* Spart = (float*)ws;                            // 8 MB
  float* meanPart = (float*)(ws + 8388608);             // 128 KB
  float* Cout = (float*)(ws + 8519680);                 // 16 KB
  unsigned short* Mb = (unsigned short*)(ws + 8536064); // 512 KB

  k_cov_partial<<<dim3(SPLIT, B_DIM), 256, 0, stream>>>(x, Spart, meanPart);
  k_chol_inv<<<dim3(B_DIM), 256, 0, stream>>>(Spart, meanPart, Mb, Cout);
  k_whiten<<<dim3(D_DIM / 256, B_DIM), 256, 0, stream>>>(x, Cout, Mb, out);
}